// Round 1
// baseline (1998.844 us; speedup 1.0000x reference)
//
#include <hip/hip_runtime.h>
#include <stdint.h>
#include <math.h>

// Problem constants
#define B_DIM 64
#define E_DIM 512
#define H_DIM 1024
#define V_DIM 32000
#define T_STEPS 31
#define GATES 4096          // 4*H
#define OUT_COLS 62         // 2*T
#define NCHUNK 125          // 32000 / 256
#define STOT 32             // K=1024 -> 32 k-steps of 32
#define TGROUP 4            // logits t-steps per batched GEMM group

// JAX >= 0.4.36 default: jax_threefry_partitionable = True
#define RNG_PARTITIONABLE 1

typedef _Float16 half8 __attribute__((ext_vector_type(8)));
typedef float floatx4 __attribute__((ext_vector_type(4)));

// ---------------- threefry2x32 (exact JAX reference) ----------------
__device__ __forceinline__ void tf_round(uint32_t& x0, uint32_t& x1, int r) {
  x0 += x1;
  x1 = (x1 << r) | (x1 >> (32 - r));
  x1 ^= x0;
}

__device__ __forceinline__ void threefry2x32(uint32_t k0, uint32_t k1,
                                             uint32_t& x0, uint32_t& x1) {
  uint32_t k2 = k0 ^ k1 ^ 0x1BD11BDAu;
  x0 += k0; x1 += k1;
  tf_round(x0,x1,13); tf_round(x0,x1,15); tf_round(x0,x1,26); tf_round(x0,x1,6);
  x0 += k1; x1 += k2 + 1u;
  tf_round(x0,x1,17); tf_round(x0,x1,29); tf_round(x0,x1,16); tf_round(x0,x1,24);
  x0 += k2; x1 += k0 + 2u;
  tf_round(x0,x1,13); tf_round(x0,x1,15); tf_round(x0,x1,26); tf_round(x0,x1,6);
  x0 += k0; x1 += k1 + 3u;
  tf_round(x0,x1,17); tf_round(x0,x1,29); tf_round(x0,x1,16); tf_round(x0,x1,24);
  x0 += k1; x1 += k2 + 4u;
  tf_round(x0,x1,13); tf_round(x0,x1,15); tf_round(x0,x1,26); tf_round(x0,x1,6);
  x0 += k2; x1 += k0 + 5u;
}

// ---------------- small utility kernels ----------------
__global__ void zero_kernel(float* __restrict__ o, int n) {
  int i = blockIdx.x * blockDim.x + threadIdx.x;
  if (i < n) o[i] = 0.0f;
}

__global__ void copy_kernel(const float* __restrict__ a, float* __restrict__ o, int n) {
  int i = blockIdx.x * blockDim.x + threadIdx.x;
  if (i < n) o[i] = a[i];
}

// ---------------- weight repack: fp32 (a [+ b]) -> f16 hi/lo MFMA B-fragments ----
__global__ __launch_bounds__(256)
void repack_w(const float* __restrict__ Wa, const float* __restrict__ Wb,
              _Float16* __restrict__ pk, int N) {
  int gw = blockIdx.x * 4 + (threadIdx.x >> 6);
  int total = (N >> 4) * STOT;
  if (gw >= total) return;
  int nt = gw >> 5, s = gw & 31;
  int lane = threadIdx.x & 63;
  int quad = lane >> 4, lm = lane & 15;
  int col = nt * 16 + lm;
  half8 hi, lo;
#pragma unroll
  for (int j = 0; j < 8; ++j) {
    int row = s * 32 + quad * 8 + j;
    float v = Wa[(size_t)row * N + col];
    if (Wb) v += Wb[(size_t)row * N + col];
    _Float16 h = (_Float16)v;
    hi[j] = h;
    lo[j] = (_Float16)(v - (float)h);
  }
  _Float16* o = pk + ((size_t)(nt * 32 + s) * 2) * 512 + lane * 8;
  *(half8*)o = hi;
  *(half8*)(o + 512) = lo;
}

// ---------------- MFMA GEMM (k-split variant, used by the state recurrence) ----
__global__ __launch_bounds__(256, 1)
void mfma_gemm(const half8* __restrict__ Apk, const half8* __restrict__ Wpk,
               float* __restrict__ P, int N) {
  const int w = threadIdx.x >> 6;
  const int lane = threadIdx.x & 63;
  const int schunk = STOT / gridDim.y;
  const int s0 = blockIdx.y * schunk;
  const int send = s0 + schunk;
  const int nt0 = blockIdx.x * 16 + w * 4;

  floatx4 acc[4][4] = {};
  half8 a0[4][2], b0[4][2], a1[4][2], b1[4][2];

#define LOAD_FRAGS(s_, A_, B_)                                              \
  {                                                                         \
    _Pragma("unroll")                                                       \
    for (int mt = 0; mt < 4; ++mt) {                                        \
      const half8* ap = Apk + ((size_t)(mt * 32 + (s_)) * 2) * 64 + lane;   \
      A_[mt][0] = ap[0];                                                    \
      A_[mt][1] = ap[64];                                                   \
    }                                                                       \
    _Pragma("unroll")                                                       \
    for (int nt = 0; nt < 4; ++nt) {                                        \
      const half8* bp =                                                     \
          Wpk + ((size_t)((nt0 + nt) * 32 + (s_)) * 2) * 64 + lane;         \
      B_[nt][0] = bp[0];                                                    \
      B_[nt][1] = bp[64];                                                   \
    }                                                                       \
  }

#define DO_MFMA(A_, B_)                                                     \
  {                                                                         \
    _Pragma("unroll")                                                       \
    for (int mt = 0; mt < 4; ++mt) {                                        \
      _Pragma("unroll")                                                     \
      for (int nt = 0; nt < 4; ++nt) {                                      \
        acc[mt][nt] = __builtin_amdgcn_mfma_f32_16x16x32_f16(               \
            A_[mt][0], B_[nt][0], acc[mt][nt], 0, 0, 0);                    \
        acc[mt][nt] = __builtin_amdgcn_mfma_f32_16x16x32_f16(               \
            A_[mt][1], B_[nt][0], acc[mt][nt], 0, 0, 0);                    \
        acc[mt][nt] = __builtin_amdgcn_mfma_f32_16x16x32_f16(               \
            A_[mt][0], B_[nt][1], acc[mt][nt], 0, 0, 0);                    \
      }                                                                     \
    }                                                                       \
  }

  LOAD_FRAGS(s0, a0, b0);
  for (int s = s0; s < send; s += 2) {
    LOAD_FRAGS(s + 1, a1, b1);
    DO_MFMA(a0, b0);
    if (s + 2 < send) LOAD_FRAGS(s + 2, a0, b0);
    DO_MFMA(a1, b1);
  }

  const int row0 = (lane >> 4) * 4;
  const int colb = blockIdx.x * 256 + w * 64 + (lane & 15);
  float* Pb = P + (size_t)blockIdx.y * 64 * N;
#pragma unroll
  for (int mt = 0; mt < 4; ++mt)
#pragma unroll
    for (int nt = 0; nt < 4; ++nt)
#pragma unroll
      for (int r = 0; r < 4; ++r)
        Pb[(size_t)(mt * 16 + row0 + r) * N + colb + nt * 16] = acc[mt][nt][r];
}

// ---------------- batched logits GEMM: full K, grid (t_local, col_chunk) ---------
// blockIdx.x = local t within group (fastest-varying -> consecutive blocks share
// the same Wd columns => L2/LLC reuse); blockIdx.y = 256-col chunk.
__global__ __launch_bounds__(256, 1)
void mfma_gemm_batch(const half8* __restrict__ ApkBase, const half8* __restrict__ Wpk,
                     float* __restrict__ P, int N) {
  const int w = threadIdx.x >> 6;
  const int lane = threadIdx.x & 63;
  const half8* Apk = ApkBase + (size_t)blockIdx.x * 16384;  // 65536 floats / slot
  const int nt0 = blockIdx.y * 16 + w * 4;

  floatx4 acc[4][4] = {};
  half8 a0[4][2], b0[4][2], a1[4][2], b1[4][2];

  LOAD_FRAGS(0, a0, b0);
  for (int s = 0; s < STOT; s += 2) {
    LOAD_FRAGS(s + 1, a1, b1);
    DO_MFMA(a0, b0);
    if (s + 2 < STOT) LOAD_FRAGS(s + 2, a0, b0);
    DO_MFMA(a1, b1);
  }
#undef LOAD_FRAGS
#undef DO_MFMA

  const int row0 = (lane >> 4) * 4;
  const int colb = blockIdx.y * 256 + w * 64 + (lane & 15);
  float* Pb = P + (size_t)blockIdx.x * 64 * N;
#pragma unroll
  for (int mt = 0; mt < 4; ++mt)
#pragma unroll
    for (int nt = 0; nt < 4; ++nt)
#pragma unroll
      for (int r = 0; r < 4; ++r)
        Pb[(size_t)(mt * 16 + row0 + r) * N + colb + nt * 16] = acc[mt][nt][r];
}

// ---------------- fp32 GEMM (encoder only, one-shot) ----------------
__global__ __launch_bounds__(256, 2)
void gemm64_kernel(const float* __restrict__ A, const float* __restrict__ W,
                   float* __restrict__ P, int K, int N) {
  const int vt = blockIdx.x;
  const int ks = blockIdx.y;
  const int kchunk = K / gridDim.y;
  const int kbase = ks * kchunk;
  const int v0 = vt * 256;

  __shared__ float As[32][68];
  __shared__ float Ws[32][256];

  float acc[8][8];
#pragma unroll
  for (int i = 0; i < 8; i++)
#pragma unroll
    for (int j = 0; j < 8; j++) acc[i][j] = 0.0f;

  const int tid = threadIdx.x;
  const int cg4 = (tid & 31) * 4;
  const int rg4 = (tid >> 5) * 4;

  for (int k0 = kbase; k0 < kbase + kchunk; k0 += 32) {
    __syncthreads();
    {
      int b  = tid >> 3;
      int f4 = tid & 7;
      const float* Ab = A + (size_t)b * K + k0 + f4 * 4;
      float4 a0 = *(const float4*)Ab;
      float4 a1 = *(const float4*)(Ab + (size_t)32 * K);
      int kk0 = f4 * 4;
      As[kk0+0][b] = a0.x; As[kk0+1][b] = a0.y; As[kk0+2][b] = a0.z; As[kk0+3][b] = a0.w;
      As[kk0+0][b+32] = a1.x; As[kk0+1][b+32] = a1.y; As[kk0+2][b+32] = a1.z; As[kk0+3][b+32] = a1.w;
    }
#pragma unroll
    for (int p = 0; p < 8; p++) {
      int idx = tid + p * 256;
      int row = idx >> 6, c4 = idx & 63;
      *(float4*)&Ws[row][c4 * 4] =
          *(const float4*)(W + (size_t)(k0 + row) * N + v0 + c4 * 4);
    }
    __syncthreads();

#pragma unroll 8
    for (int kk = 0; kk < 32; kk++) {
      float4 a0 = *(const float4*)&As[kk][rg4];
      float4 a1 = *(const float4*)&As[kk][32 + rg4];
      float4 w0 = *(const float4*)&Ws[kk][cg4];
      float4 w1 = *(const float4*)&Ws[kk][128 + cg4];
      float av[8] = {a0.x, a0.y, a0.z, a0.w, a1.x, a1.y, a1.z, a1.w};
      float wv[8] = {w0.x, w0.y, w0.z, w0.w, w1.x, w1.y, w1.z, w1.w};
#pragma unroll
      for (int i = 0; i < 8; i++)
#pragma unroll
        for (int j = 0; j < 8; j++)
          acc[i][j] = fmaf(av[i], wv[j], acc[i][j]);
    }
  }

  const size_t base = (size_t)ks * 64 * N;
#pragma unroll
  for (int i = 0; i < 8; i++) {
    int row = (i < 4) ? (rg4 + i) : (32 + rg4 + i - 4);
    float4 s0 = make_float4(acc[i][0], acc[i][1], acc[i][2], acc[i][3]);
    float4 s1 = make_float4(acc[i][4], acc[i][5], acc[i][6], acc[i][7]);
    *(float4*)(P + base + (size_t)row * N + v0 + cg4) = s0;
    *(float4*)(P + base + (size_t)row * N + v0 + 128 + cg4) = s1;
  }
}

// ---------------- LSTM gate fusion + A-fragment pack ----------------
__global__ void gates_kernel(const float* __restrict__ zp, int ksplit,
                             const float* __restrict__ bias,
                             const float* __restrict__ c_in,
                             float* __restrict__ h_out, float* __restrict__ c_out,
                             _Float16* __restrict__ hpk) {
  int tid = blockIdx.x * blockDim.x + threadIdx.x;
  if (tid >= B_DIM * H_DIM) return;
  int b = tid >> 10, j = tid & 1023;
  float zi = bias[j], zf = bias[j + 1024], zg = bias[j + 2048], zo = bias[j + 3072];
  const float* Pb = zp + (size_t)b * GATES;
  for (int p = 0; p < ksplit; p++) {
    const float* P = Pb + (size_t)p * B_DIM * GATES;
    zi += P[j]; zf += P[j + 1024]; zg += P[j + 2048]; zo += P[j + 3072];
  }
  float cp = c_in ? c_in[tid] : 0.0f;
  float si = 1.0f / (1.0f + expf(-zi));
  float sf = 1.0f / (1.0f + expf(-zf));
  float so = 1.0f / (1.0f + expf(-zo));
  float c = sf * cp + si * zg;
  c_out[tid] = c;
  float hv = so * c;
  h_out[tid] = hv;

  int mt = b >> 4, lm = b & 15;
  int s = j >> 5, quad = (j >> 3) & 3, jj = j & 7;
  size_t off = ((size_t)(mt * 32 + s) * 2) * 512 + (size_t)(quad * 16 + lm) * 8 + jj;
  _Float16 hh = (_Float16)hv;
  hpk[off] = hh;
  hpk[off + 512] = (_Float16)(hv - (float)hh);
}

// ---------------- batched sampling stage 1: per-chunk partials over a t-group ---
__global__ __launch_bounds__(256)
void sample_stage1_batch(const float* __restrict__ lbuf, const float* __restrict__ bd,
                         int t0, int gsz,
                         float* __restrict__ pm, float* __restrict__ ps,
                         float* __restrict__ pt2, float* __restrict__ pbest,
                         float* __restrict__ plb, int* __restrict__ pbi) {
  const int chunk = blockIdx.x;
  const int b = blockIdx.y;
  const int v = chunk * 256 + threadIdx.x;
  const float lbias = bd[v];
  const int wave = threadIdx.x >> 6, lane = threadIdx.x & 63;

  __shared__ float sm[4], sb2[4], slb[4], ss[4], st[4];
  __shared__ int sbi[4];
  __shared__ float Msh;

  for (int lt = 0; lt < gsz; ++lt) {
    const int t = t0 + lt;
    float l = lbias + lbuf[(size_t)lt * B_DIM * V_DIM + (size_t)b * V_DIM + v];

    uint32_t tk0 = 0u, tk1 = (uint32_t)t;
    threefry2x32(0u, 1234u, tk0, tk1);
    uint32_t j = (uint32_t)(b * V_DIM + v);
#if RNG_PARTITIONABLE
    uint32_t y0 = 0u, y1 = j;
    threefry2x32(tk0, tk1, y0, y1);
    uint32_t bits = y0 ^ y1;
#else
    const uint32_t half = (uint32_t)(B_DIM * V_DIM / 2);
    uint32_t y0, y1;
    if (j < half) { y0 = j; y1 = j + half; } else { y0 = j - half; y1 = j; }
    threefry2x32(tk0, tk1, y0, y1);
    uint32_t bits = (j < half) ? y0 : y1;
#endif
    float u = __uint_as_float((bits >> 9) | 0x3f800000u) - 1.0f;
    u = fmaxf(u, 1.17549435e-38f);
    float g = -logf(-logf(u));
    float val = l + g;
    int bi = v;
    float bv = val, blv = l;

    float m = l;
    for (int off = 32; off > 0; off >>= 1) {
      m = fmaxf(m, __shfl_down(m, off));
      float ob = __shfl_down(bv, off);
      int   oi = __shfl_down(bi, off);
      float ol = __shfl_down(blv, off);
      if (ob > bv || (ob == bv && oi < bi)) { bv = ob; bi = oi; blv = ol; }
    }
    __syncthreads();  // guard shared reuse across lt iterations
    if (lane == 0) { sm[wave] = m; sb2[wave] = bv; sbi[wave] = bi; slb[wave] = blv; }
    __syncthreads();
    if (threadIdx.x == 0) {
      float M = sm[0], Bv = sb2[0], Bl = slb[0]; int BI = sbi[0];
      for (int w2 = 1; w2 < 4; w2++) {
        M = fmaxf(M, sm[w2]);
        if (sb2[w2] > Bv || (sb2[w2] == Bv && sbi[w2] < BI)) {
          Bv = sb2[w2]; BI = sbi[w2]; Bl = slb[w2];
        }
      }
      Msh = M;
      size_t o = ((size_t)t * B_DIM + b) * NCHUNK + chunk;
      pm[o] = M; pbest[o] = Bv; pbi[o] = BI; plb[o] = Bl;
    }
    __syncthreads();
    float e = expf(l - Msh);
    float t2 = e * l;
    for (int off = 32; off > 0; off >>= 1) {
      e  += __shfl_down(e, off);
      t2 += __shfl_down(t2, off);
    }
    if (lane == 0) { ss[wave] = e; st[wave] = t2; }
    __syncthreads();
    if (threadIdx.x == 0) {
      size_t o = ((size_t)t * B_DIM + b) * NCHUNK + chunk;
      ps[o]  = ss[0] + ss[1] + ss[2] + ss[3];
      pt2[o] = st[0] + st[1] + st[2] + st[3];
    }
  }
}

// ---------------- batched sampling stage 2: reduce 125 chunks per (b,t) ---------
__global__ __launch_bounds__(128)
void sample_stage2_batch(const float* __restrict__ pm, const float* __restrict__ ps,
                         const float* __restrict__ pt2, const float* __restrict__ pbest,
                         const float* __restrict__ plb, const int* __restrict__ pbi,
                         float* __restrict__ out) {
  const int b = blockIdx.x;
  const int t = blockIdx.y;
  const int tid = threadIdx.x;
  const size_t base = ((size_t)t * B_DIM + b) * NCHUNK;
  const bool valid = tid < NCHUNK;

  float m   = valid ? pm[base + tid]    : -INFINITY;
  float bv  = valid ? pbest[base + tid] : -INFINITY;
  float blv = valid ? plb[base + tid]   : 0.0f;
  int   bi  = valid ? pbi[base + tid]   : 0x7fffffff;

  float M = m;
  for (int off = 32; off > 0; off >>= 1) M = fmaxf(M, __shfl_down(M, off));
  __shared__ float sM[2];
  int wave = tid >> 6, lane = tid & 63;
  if (lane == 0) sM[wave] = M;
  __syncthreads();
  const float Mg = fmaxf(sM[0], sM[1]);

  float sc = valid ? expf(m - Mg) : 0.0f;
  float s  = valid ? ps[base + tid]  * sc : 0.0f;
  float t2 = valid ? pt2[base + tid] * sc : 0.0f;
  for (int off = 32; off > 0; off >>= 1) {
    s  += __shfl_down(s, off);
    t2 += __shfl_down(t2, off);
    float ob = __shfl_down(bv, off);
    int   oi = __shfl_down(bi, off);
    float ol = __shfl_down(blv, off);
    if (ob > bv || (ob == bv && oi < bi)) { bv = ob; bi = oi; blv = ol; }
  }
  __shared__ float sS[2], sT[2], sB[2], sL[2];
  __shared__ int sI[2];
  if (lane == 0) { sS[wave] = s; sT[wave] = t2; sB[wave] = bv; sI[wave] = bi; sL[wave] = blv; }
  __syncthreads();
  if (tid == 0) {
    float S = sS[0] + sS[1], T2 = sT[0] + sT[1];
    float Bv = sB[0], Bl = sL[0]; int BI = sI[0];
    if (sB[1] > Bv || (sB[1] == Bv && sI[1] < BI)) { Bv = sB[1]; BI = sI[1]; Bl = sL[1]; }
    float lse = Mg + logf(S);
    out[(size_t)b * OUT_COLS + t]        = (float)BI;   // msg
    out[3968 + (size_t)b * OUT_COLS + t] = Bl - lse;    // log_prob
    out[7936 + (size_t)b * OUT_COLS + t] = lse - T2 / S; // entropy
  }
}

// ---------------- launcher ----------------
extern "C" void kernel_launch(void* const* d_in, const int* in_sizes, int n_in,
                              void* d_out, int out_size, void* d_ws, size_t ws_size,
                              hipStream_t stream) {
  const float* inp = (const float*)d_in[0];
  const float* Wx1 = (const float*)d_in[1];
  // d_in[2] = Wh1: unused (encoder initial h == 0)
  const float* b1  = (const float*)d_in[3];
  const float* Wx2 = (const float*)d_in[4];
  const float* Wh2 = (const float*)d_in[5];
  const float* b2  = (const float*)d_in[6];
  const float* Wd  = (const float*)d_in[7];
  const float* bd  = (const float*)d_in[8];
  float* out = (float*)d_out;

  float* ws = (float*)d_ws;
  float* Wd_pk  = ws;                    // 32,768,000 floats (131 MB f16 hi/lo)
  float* W2_pk  = Wd_pk + 32768000;      //  4,194,304
  float* hpkA   = W2_pk + 4194304;       //  2,097,152 (32 slots x 65,536: h_0..h_31 packed)
  float* zparts = hpkA + 2097152;        //  2,097,152 (8 k-split parts; partials alias)
  float* lbuf   = zparts + 2097152;      //  8,192,000 (TGROUP x 64 x 32000 logits)
  float* h      = lbuf + 8192000;        //     65,536
  float* c      = h + 65536;             //     65,536

  // sampling partials alias zparts (dead after the recurrence phase)
  // 31*64*125 = 248,000 entries each; 6 arrays = 1,488,000 floats <= 2,097,152
  float* pm    = zparts;
  float* ps    = zparts + 248000;
  float* pt2   = zparts + 496000;
  float* pbest = zparts + 744000;
  float* plb   = zparts + 992000;
  int*   pbi   = (int*)(zparts + 1240000);

  // one-time: repack Wd and (Wx2+Wh2) into f16 hi/lo MFMA fragments
  repack_w<<<16000, 256, 0, stream>>>(Wd, nullptr, (_Float16*)Wd_pk, V_DIM);
  repack_w<<<2048, 256, 0, stream>>>(Wx2, Wh2, (_Float16*)W2_pk, GATES);
  zero_kernel<<<47, 256, 0, stream>>>(out, 11904);

  // encoder: single step, zero initial state -> z = x@Wx1 + b1 (fp32, one-shot)
  gemm64_kernel<<<dim3(16, 4), 256, 0, stream>>>(inp, Wx1, zparts, E_DIM, GATES);
  gates_kernel<<<256, 256, 0, stream>>>(zparts, 4, b1, nullptr, h, c,
                                        (_Float16*)hpkA);  // slot 0 = h_0

  // Phase A: pure state recurrence. h_{t+1} = lstm(h_t); sampling never feeds back,
  // so we only compute/pack the hidden trajectory here (slots 1..31).
  for (int t = 0; t < T_STEPS; t++) {
    mfma_gemm<<<dim3(16, 8), 256, 0, stream>>>(
        (const half8*)(hpkA + (size_t)t * 65536), (const half8*)W2_pk,
        zparts, GATES);
    gates_kernel<<<256, 256, 0, stream>>>(
        zparts, 8, b2, c, h, c, (_Float16*)(hpkA + (size_t)(t + 1) * 65536));
  }

  // Phase B: batched logits GEMM + sampling stage 1, in groups of TGROUP t-steps.
  // Wd_pk (131 MB) is read from HBM once and stays LLC-resident across groups;
  // within a group, blockIdx.x (=t) varies fastest so consecutive blocks share
  // the same Wd columns (L2 reuse). Full K per block: no k-split partial traffic.
  for (int t0 = 0; t0 < T_STEPS; t0 += TGROUP) {
    int gsz = T_STEPS - t0;
    if (gsz > TGROUP) gsz = TGROUP;
    // logits for decode step t come from h_{t+1} -> slot t0+1
    mfma_gemm_batch<<<dim3(gsz, 125), 256, 0, stream>>>(
        (const half8*)(hpkA + (size_t)(t0 + 1) * 65536), (const half8*)Wd_pk,
        lbuf, V_DIM);
    sample_stage1_batch<<<dim3(NCHUNK, B_DIM), 256, 0, stream>>>(
        lbuf, bd, t0, gsz, pm, ps, pt2, pbest, plb, pbi);
  }

  // Phase C: one batched stage-2 reduction for all (b, t)
  sample_stage2_batch<<<dim3(B_DIM, T_STEPS), 128, 0, stream>>>(
      pm, ps, pt2, pbest, plb, pbi, out);

  copy_kernel<<<256, 256, 0, stream>>>(h, out + 11904, B_DIM * H_DIM);
}

// Round 2
// 1587.972 us; speedup vs baseline: 1.2587x; 1.2587x over previous
//
#include <hip/hip_runtime.h>
#include <stdint.h>
#include <math.h>

// Problem constants
#define B_DIM 64
#define E_DIM 512
#define H_DIM 1024
#define V_DIM 32000
#define T_STEPS 31
#define GATES 4096          // 4*H
#define OUT_COLS 62         // 2*T
#define NCHUNK 125          // 32000 / 256
#define STOT 32             // K=1024 -> 32 k-steps of 32

// JAX >= 0.4.36 default: jax_threefry_partitionable = True
#define RNG_PARTITIONABLE 1

typedef _Float16 half8 __attribute__((ext_vector_type(8)));
typedef float floatx4 __attribute__((ext_vector_type(4)));

// ---------------- threefry2x32 (exact JAX reference) ----------------
__device__ __forceinline__ void tf_round(uint32_t& x0, uint32_t& x1, int r) {
  x0 += x1;
  x1 = (x1 << r) | (x1 >> (32 - r));
  x1 ^= x0;
}

__device__ __forceinline__ void threefry2x32(uint32_t k0, uint32_t k1,
                                             uint32_t& x0, uint32_t& x1) {
  uint32_t k2 = k0 ^ k1 ^ 0x1BD11BDAu;
  x0 += k0; x1 += k1;
  tf_round(x0,x1,13); tf_round(x0,x1,15); tf_round(x0,x1,26); tf_round(x0,x1,6);
  x0 += k1; x1 += k2 + 1u;
  tf_round(x0,x1,17); tf_round(x0,x1,29); tf_round(x0,x1,16); tf_round(x0,x1,24);
  x0 += k2; x1 += k0 + 2u;
  tf_round(x0,x1,13); tf_round(x0,x1,15); tf_round(x0,x1,26); tf_round(x0,x1,6);
  x0 += k0; x1 += k1 + 3u;
  tf_round(x0,x1,17); tf_round(x0,x1,29); tf_round(x0,x1,16); tf_round(x0,x1,24);
  x0 += k1; x1 += k2 + 4u;
  tf_round(x0,x1,13); tf_round(x0,x1,15); tf_round(x0,x1,26); tf_round(x0,x1,6);
  x0 += k2; x1 += k0 + 5u;
}

// ---------------- small utility kernels ----------------
__global__ void zero_kernel(float* __restrict__ o, int n) {
  int i = blockIdx.x * blockDim.x + threadIdx.x;
  if (i < n) o[i] = 0.0f;
}

__global__ void copy_kernel(const float* __restrict__ a, float* __restrict__ o, int n) {
  int i = blockIdx.x * blockDim.x + threadIdx.x;
  if (i < n) o[i] = a[i];
}

// ---------------- weight repack: fp32 (a [+ b]) -> f16 hi/lo MFMA B-fragments ----
__global__ __launch_bounds__(256)
void repack_w(const float* __restrict__ Wa, const float* __restrict__ Wb,
              _Float16* __restrict__ pk, int N) {
  int gw = blockIdx.x * 4 + (threadIdx.x >> 6);
  int total = (N >> 4) * STOT;
  if (gw >= total) return;
  int nt = gw >> 5, s = gw & 31;
  int lane = threadIdx.x & 63;
  int quad = lane >> 4, lm = lane & 15;
  int col = nt * 16 + lm;
  half8 hi, lo;
#pragma unroll
  for (int j = 0; j < 8; ++j) {
    int row = s * 32 + quad * 8 + j;
    float v = Wa[(size_t)row * N + col];
    if (Wb) v += Wb[(size_t)row * N + col];
    _Float16 h = (_Float16)v;
    hi[j] = h;
    lo[j] = (_Float16)(v - (float)h);
  }
  _Float16* o = pk + ((size_t)(nt * 32 + s) * 2) * 512 + lane * 8;
  *(half8*)o = hi;
  *(half8*)(o + 512) = lo;
}

// Shared fragment-load / MFMA macros (used by both MFMA GEMM kernels).
#define LOAD_FRAGS(s_, A_, B_)                                              \
  {                                                                         \
    _Pragma("unroll")                                                       \
    for (int mt = 0; mt < 4; ++mt) {                                        \
      const half8* ap = Apk + ((size_t)(mt * 32 + (s_)) * 2) * 64 + lane;   \
      A_[mt][0] = ap[0];                                                    \
      A_[mt][1] = ap[64];                                                   \
    }                                                                       \
    _Pragma("unroll")                                                       \
    for (int nt = 0; nt < 4; ++nt) {                                        \
      const half8* bp =                                                     \
          Wpk + ((size_t)((nt0 + nt) * 32 + (s_)) * 2) * 64 + lane;         \
      B_[nt][0] = bp[0];                                                    \
      B_[nt][1] = bp[64];                                                   \
    }                                                                       \
  }

#define DO_MFMA(A_, B_)                                                     \
  {                                                                         \
    _Pragma("unroll")                                                       \
    for (int mt = 0; mt < 4; ++mt) {                                        \
      _Pragma("unroll")                                                     \
      for (int nt = 0; nt < 4; ++nt) {                                      \
        acc[mt][nt] = __builtin_amdgcn_mfma_f32_16x16x32_f16(               \
            A_[mt][0], B_[nt][0], acc[mt][nt], 0, 0, 0);                    \
        acc[mt][nt] = __builtin_amdgcn_mfma_f32_16x16x32_f16(               \
            A_[mt][1], B_[nt][0], acc[mt][nt], 0, 0, 0);                    \
        acc[mt][nt] = __builtin_amdgcn_mfma_f32_16x16x32_f16(               \
            A_[mt][0], B_[nt][1], acc[mt][nt], 0, 0, 0);                    \
      }                                                                     \
    }                                                                       \
  }

// ---------------- MFMA GEMM (k-split variant, used by the state recurrence) ----
__global__ __launch_bounds__(256, 1)
void mfma_gemm(const half8* __restrict__ Apk, const half8* __restrict__ Wpk,
               float* __restrict__ P, int N) {
  const int w = threadIdx.x >> 6;
  const int lane = threadIdx.x & 63;
  const int schunk = STOT / gridDim.y;
  const int s0 = blockIdx.y * schunk;
  const int send = s0 + schunk;
  const int nt0 = blockIdx.x * 16 + w * 4;

  floatx4 acc[4][4] = {};
  half8 a0[4][2], b0[4][2], a1[4][2], b1[4][2];

  LOAD_FRAGS(s0, a0, b0);
  for (int s = s0; s < send; s += 2) {
    LOAD_FRAGS(s + 1, a1, b1);
    DO_MFMA(a0, b0);
    if (s + 2 < send) LOAD_FRAGS(s + 2, a0, b0);
    DO_MFMA(a1, b1);
  }

  const int row0 = (lane >> 4) * 4;
  const int colb = blockIdx.x * 256 + w * 64 + (lane & 15);
  float* Pb = P + (size_t)blockIdx.y * 64 * N;
#pragma unroll
  for (int mt = 0; mt < 4; ++mt)
#pragma unroll
    for (int nt = 0; nt < 4; ++nt)
#pragma unroll
      for (int r = 0; r < 4; ++r)
        Pb[(size_t)(mt * 16 + row0 + r) * N + colb + nt * 16] = acc[mt][nt][r];
}

// ---------------- fused logits GEMM + sampling stage 1 ----------------
// One dispatch for all t. Grid: blockIdx.x = t (0..30, fastest-varying so
// consecutive blocks share the same Wd columns -> L2/LLC reuse; Wd streams
// from HBM once), blockIdx.y = 256-col vocab chunk. Full K per block.
// Epilogue computes per-(t,b,chunk) stage-1 partials in-register + LDS:
// row max M, sum e^(l-M), sum l*e^(l-M), Gumbel argmax (val, idx, logit).
// The 254 MB logits tensor is never materialized.
__global__ __launch_bounds__(256, 1)
void mfma_logits_fused(const half8* __restrict__ hpkA, const half8* __restrict__ Wpk,
                       const float* __restrict__ bd,
                       float* __restrict__ pm, float* __restrict__ ps,
                       float* __restrict__ pt2, float* __restrict__ pbest,
                       float* __restrict__ plb, int* __restrict__ pbi) {
  const int t = blockIdx.x;
  const int chunk = blockIdx.y;
  const int w = threadIdx.x >> 6;
  const int lane = threadIdx.x & 63;
  const int lm = lane & 15, q = lane >> 4;
  const half8* Apk = hpkA + (size_t)(t + 1) * 16384;  // h_{t+1} slot
  const int nt0 = chunk * 16 + w * 4;

  floatx4 acc[4][4] = {};
  half8 a0[4][2], b0[4][2], a1[4][2], b1[4][2];

  LOAD_FRAGS(0, a0, b0);
  for (int s = 0; s < STOT; s += 2) {
    LOAD_FRAGS(s + 1, a1, b1);
    DO_MFMA(a0, b0);
    if (s + 2 < STOT) LOAD_FRAGS(s + 2, a0, b0);
    DO_MFMA(a1, b1);
  }

  // ---------- epilogue: bias + stage-1 partials ----------
  const int colb = chunk * 256 + w * 64 + lm;

  float bdv[4];
#pragma unroll
  for (int nt = 0; nt < 4; ++nt) bdv[nt] = bd[colb + nt * 16];
#pragma unroll
  for (int mt = 0; mt < 4; ++mt)
#pragma unroll
    for (int nt = 0; nt < 4; ++nt)
#pragma unroll
      for (int r = 0; r < 4; ++r) acc[mt][nt][r] += bdv[nt];

  __shared__ float redM[4][64];
  __shared__ float redS[4][64], redT[4][64], redBV[4][64], redBL[4][64];
  __shared__ int   redBI[4][64];

  // per-row max over this block's 256 cols (in-lane 4, 16-lane xor tree, LDS x4 waves)
  float M[4][4];
#pragma unroll
  for (int mt = 0; mt < 4; ++mt) {
#pragma unroll
    for (int r = 0; r < 4; ++r) {
      float m = fmaxf(fmaxf(acc[mt][0][r], acc[mt][1][r]),
                      fmaxf(acc[mt][2][r], acc[mt][3][r]));
#pragma unroll
      for (int off = 1; off <= 8; off <<= 1) m = fmaxf(m, __shfl_xor(m, off));
      if (lm == 0) redM[w][mt * 16 + q * 4 + r] = m;
      M[mt][r] = m;  // placeholder; finalized after barrier
    }
  }
  __syncthreads();
#pragma unroll
  for (int mt = 0; mt < 4; ++mt)
#pragma unroll
    for (int r = 0; r < 4; ++r) {
      int b = mt * 16 + q * 4 + r;
      M[mt][r] = fmaxf(fmaxf(redM[0][b], redM[1][b]),
                       fmaxf(redM[2][b], redM[3][b]));
    }

  // threefry key for this t (uniform per block)
  uint32_t tk0 = 0u, tk1 = (uint32_t)t;
  threefry2x32(0u, 1234u, tk0, tk1);

#pragma unroll
  for (int mt = 0; mt < 4; ++mt) {
#pragma unroll
    for (int r = 0; r < 4; ++r) {
      const int b = mt * 16 + q * 4 + r;
      const float Mrow = M[mt][r];
      float s = 0.f, t2 = 0.f, bv = -INFINITY, bl = 0.f;
      int bi = 0x7fffffff;
#pragma unroll
      for (int nt = 0; nt < 4; ++nt) {
        float l = acc[mt][nt][r];
        int v = colb + nt * 16;
        float e = expf(l - Mrow);
        s += e;
        t2 += e * l;
        uint32_t j = (uint32_t)(b * V_DIM + v);
#if RNG_PARTITIONABLE
        uint32_t y0 = 0u, y1 = j;
        threefry2x32(tk0, tk1, y0, y1);
        uint32_t bits = y0 ^ y1;
#else
        const uint32_t half = (uint32_t)(B_DIM * V_DIM / 2);
        uint32_t y0, y1;
        if (j < half) { y0 = j; y1 = j + half; } else { y0 = j - half; y1 = j; }
        threefry2x32(tk0, tk1, y0, y1);
        uint32_t bits = (j < half) ? y0 : y1;
#endif
        float u = __uint_as_float((bits >> 9) | 0x3f800000u) - 1.0f;
        u = fmaxf(u, 1.17549435e-38f);
        float g = -logf(-logf(u));
        float val = l + g;
        if (val > bv || (val == bv && v < bi)) { bv = val; bi = v; bl = l; }
      }
      // 16-lane xor reduce (sum / argmax)
#pragma unroll
      for (int off = 1; off <= 8; off <<= 1) {
        s  += __shfl_xor(s, off);
        t2 += __shfl_xor(t2, off);
        float ob = __shfl_xor(bv, off);
        int   oi = __shfl_xor(bi, off);
        float ol = __shfl_xor(bl, off);
        if (ob > bv || (ob == bv && oi < bi)) { bv = ob; bi = oi; bl = ol; }
      }
      if (lm == 0) {
        redS[w][b] = s; redT[w][b] = t2;
        redBV[w][b] = bv; redBI[w][b] = bi; redBL[w][b] = bl;
      }
    }
  }
  __syncthreads();
  // final cross-wave combine: wave 0, lane = row b
  if (w == 0) {
    int b = lane;
    float Mg = fmaxf(fmaxf(redM[0][b], redM[1][b]),
                     fmaxf(redM[2][b], redM[3][b]));
    float S  = redS[0][b] + redS[1][b] + redS[2][b] + redS[3][b];
    float T2 = redT[0][b] + redT[1][b] + redT[2][b] + redT[3][b];
    float Bv = redBV[0][b]; int BI = redBI[0][b]; float Bl = redBL[0][b];
#pragma unroll
    for (int ww = 1; ww < 4; ++ww) {
      if (redBV[ww][b] > Bv || (redBV[ww][b] == Bv && redBI[ww][b] < BI)) {
        Bv = redBV[ww][b]; BI = redBI[ww][b]; Bl = redBL[ww][b];
      }
    }
    size_t o = ((size_t)t * B_DIM + b) * NCHUNK + chunk;
    pm[o] = Mg; ps[o] = S; pt2[o] = T2; pbest[o] = Bv; plb[o] = Bl;
    pbi[o] = BI;
  }
}

#undef LOAD_FRAGS
#undef DO_MFMA

// ---------------- fp32 GEMM (encoder only, one-shot) ----------------
__global__ __launch_bounds__(256, 2)
void gemm64_kernel(const float* __restrict__ A, const float* __restrict__ W,
                   float* __restrict__ P, int K, int N) {
  const int vt = blockIdx.x;
  const int ks = blockIdx.y;
  const int kchunk = K / gridDim.y;
  const int kbase = ks * kchunk;
  const int v0 = vt * 256;

  __shared__ float As[32][68];
  __shared__ float Ws[32][256];

  float acc[8][8];
#pragma unroll
  for (int i = 0; i < 8; i++)
#pragma unroll
    for (int j = 0; j < 8; j++) acc[i][j] = 0.0f;

  const int tid = threadIdx.x;
  const int cg4 = (tid & 31) * 4;
  const int rg4 = (tid >> 5) * 4;

  for (int k0 = kbase; k0 < kbase + kchunk; k0 += 32) {
    __syncthreads();
    {
      int b  = tid >> 3;
      int f4 = tid & 7;
      const float* Ab = A + (size_t)b * K + k0 + f4 * 4;
      float4 a0 = *(const float4*)Ab;
      float4 a1 = *(const float4*)(Ab + (size_t)32 * K);
      int kk0 = f4 * 4;
      As[kk0+0][b] = a0.x; As[kk0+1][b] = a0.y; As[kk0+2][b] = a0.z; As[kk0+3][b] = a0.w;
      As[kk0+0][b+32] = a1.x; As[kk0+1][b+32] = a1.y; As[kk0+2][b+32] = a1.z; As[kk0+3][b+32] = a1.w;
    }
#pragma unroll
    for (int p = 0; p < 8; p++) {
      int idx = tid + p * 256;
      int row = idx >> 6, c4 = idx & 63;
      *(float4*)&Ws[row][c4 * 4] =
          *(const float4*)(W + (size_t)(k0 + row) * N + v0 + c4 * 4);
    }
    __syncthreads();

#pragma unroll 8
    for (int kk = 0; kk < 32; kk++) {
      float4 a0 = *(const float4*)&As[kk][rg4];
      float4 a1 = *(const float4*)&As[kk][32 + rg4];
      float4 w0 = *(const float4*)&Ws[kk][cg4];
      float4 w1 = *(const float4*)&Ws[kk][128 + cg4];
      float av[8] = {a0.x, a0.y, a0.z, a0.w, a1.x, a1.y, a1.z, a1.w};
      float wv[8] = {w0.x, w0.y, w0.z, w0.w, w1.x, w1.y, w1.z, w1.w};
#pragma unroll
      for (int i = 0; i < 8; i++)
#pragma unroll
        for (int j = 0; j < 8; j++)
          acc[i][j] = fmaf(av[i], wv[j], acc[i][j]);
    }
  }

  const size_t base = (size_t)ks * 64 * N;
#pragma unroll
  for (int i = 0; i < 8; i++) {
    int row = (i < 4) ? (rg4 + i) : (32 + rg4 + i - 4);
    float4 s0 = make_float4(acc[i][0], acc[i][1], acc[i][2], acc[i][3]);
    float4 s1 = make_float4(acc[i][4], acc[i][5], acc[i][6], acc[i][7]);
    *(float4*)(P + base + (size_t)row * N + v0 + cg4) = s0;
    *(float4*)(P + base + (size_t)row * N + v0 + 128 + cg4) = s1;
  }
}

// ---------------- LSTM gate fusion + A-fragment pack ----------------
__global__ void gates_kernel(const float* __restrict__ zp, int ksplit,
                             const float* __restrict__ bias,
                             const float* __restrict__ c_in,
                             float* __restrict__ h_out, float* __restrict__ c_out,
                             _Float16* __restrict__ hpk) {
  int tid = blockIdx.x * blockDim.x + threadIdx.x;
  if (tid >= B_DIM * H_DIM) return;
  int b = tid >> 10, j = tid & 1023;
  float zi = bias[j], zf = bias[j + 1024], zg = bias[j + 2048], zo = bias[j + 3072];
  const float* Pb = zp + (size_t)b * GATES;
  for (int p = 0; p < ksplit; p++) {
    const float* P = Pb + (size_t)p * B_DIM * GATES;
    zi += P[j]; zf += P[j + 1024]; zg += P[j + 2048]; zo += P[j + 3072];
  }
  float cp = c_in ? c_in[tid] : 0.0f;
  float si = 1.0f / (1.0f + expf(-zi));
  float sf = 1.0f / (1.0f + expf(-zf));
  float so = 1.0f / (1.0f + expf(-zo));
  float c = sf * cp + si * zg;
  c_out[tid] = c;
  float hv = so * c;
  h_out[tid] = hv;

  int mt = b >> 4, lm = b & 15;
  int s = j >> 5, quad = (j >> 3) & 3, jj = j & 7;
  size_t off = ((size_t)(mt * 32 + s) * 2) * 512 + (size_t)(quad * 16 + lm) * 8 + jj;
  _Float16 hh = (_Float16)hv;
  hpk[off] = hh;
  hpk[off + 512] = (_Float16)(hv - (float)hh);
}

// ---------------- batched sampling stage 2: reduce 125 chunks per (b,t) ---------
__global__ __launch_bounds__(128)
void sample_stage2_batch(const float* __restrict__ pm, const float* __restrict__ ps,
                         const float* __restrict__ pt2, const float* __restrict__ pbest,
                         const float* __restrict__ plb, const int* __restrict__ pbi,
                         float* __restrict__ out) {
  const int b = blockIdx.x;
  const int t = blockIdx.y;
  const int tid = threadIdx.x;
  const size_t base = ((size_t)t * B_DIM + b) * NCHUNK;
  const bool valid = tid < NCHUNK;

  float m   = valid ? pm[base + tid]    : -INFINITY;
  float bv  = valid ? pbest[base + tid] : -INFINITY;
  float blv = valid ? plb[base + tid]   : 0.0f;
  int   bi  = valid ? pbi[base + tid]   : 0x7fffffff;

  float M = m;
  for (int off = 32; off > 0; off >>= 1) M = fmaxf(M, __shfl_down(M, off));
  __shared__ float sM[2];
  int wave = tid >> 6, lane = tid & 63;
  if (lane == 0) sM[wave] = M;
  __syncthreads();
  const float Mg = fmaxf(sM[0], sM[1]);

  float sc = valid ? expf(m - Mg) : 0.0f;
  float s  = valid ? ps[base + tid]  * sc : 0.0f;
  float t2 = valid ? pt2[base + tid] * sc : 0.0f;
  for (int off = 32; off > 0; off >>= 1) {
    s  += __shfl_down(s, off);
    t2 += __shfl_down(t2, off);
    float ob = __shfl_down(bv, off);
    int   oi = __shfl_down(bi, off);
    float ol = __shfl_down(blv, off);
    if (ob > bv || (ob == bv && oi < bi)) { bv = ob; bi = oi; blv = ol; }
  }
  __shared__ float sS[2], sT[2], sB[2], sL[2];
  __shared__ int sI[2];
  if (lane == 0) { sS[wave] = s; sT[wave] = t2; sB[wave] = bv; sI[wave] = bi; sL[wave] = blv; }
  __syncthreads();
  if (tid == 0) {
    float S = sS[0] + sS[1], T2 = sT[0] + sT[1];
    float Bv = sB[0], Bl = sL[0]; int BI = sI[0];
    if (sB[1] > Bv || (sB[1] == Bv && sI[1] < BI)) { Bv = sB[1]; BI = sI[1]; Bl = sL[1]; }
    float lse = Mg + logf(S);
    out[(size_t)b * OUT_COLS + t]        = (float)BI;    // msg
    out[3968 + (size_t)b * OUT_COLS + t] = Bl - lse;     // log_prob
    out[7936 + (size_t)b * OUT_COLS + t] = lse - T2 / S; // entropy
  }
}

// ---------------- launcher ----------------
extern "C" void kernel_launch(void* const* d_in, const int* in_sizes, int n_in,
                              void* d_out, int out_size, void* d_ws, size_t ws_size,
                              hipStream_t stream) {
  const float* inp = (const float*)d_in[0];
  const float* Wx1 = (const float*)d_in[1];
  // d_in[2] = Wh1: unused (encoder initial h == 0)
  const float* b1  = (const float*)d_in[3];
  const float* Wx2 = (const float*)d_in[4];
  const float* Wh2 = (const float*)d_in[5];
  const float* b2  = (const float*)d_in[6];
  const float* Wd  = (const float*)d_in[7];
  const float* bd  = (const float*)d_in[8];
  float* out = (float*)d_out;

  float* ws = (float*)d_ws;
  float* Wd_pk  = ws;                    // 32,768,000 floats (131 MB f16 hi/lo)
  float* W2_pk  = Wd_pk + 32768000;      //  4,194,304
  float* hpkA   = W2_pk + 4194304;       //  2,097,152 (32 slots x 65,536: h_0..h_31 packed)
  float* zparts = hpkA + 2097152;        //  2,097,152 (8 k-split parts; partials alias)
  float* h      = zparts + 2097152;      //     65,536
  float* c      = h + 65536;             //     65,536

  // sampling partials alias zparts (dead after the recurrence phase)
  // 31*64*125 = 248,000 entries each; 6 arrays = 1,488,000 floats <= 2,097,152
  float* pm    = zparts;
  float* ps    = zparts + 248000;
  float* pt2   = zparts + 496000;
  float* pbest = zparts + 744000;
  float* plb   = zparts + 992000;
  int*   pbi   = (int*)(zparts + 1240000);

  // one-time: repack Wd and (Wx2+Wh2) into f16 hi/lo MFMA fragments
  repack_w<<<16000, 256, 0, stream>>>(Wd, nullptr, (_Float16*)Wd_pk, V_DIM);
  repack_w<<<2048, 256, 0, stream>>>(Wx2, Wh2, (_Float16*)W2_pk, GATES);
  zero_kernel<<<47, 256, 0, stream>>>(out, 11904);

  // encoder: single step, zero initial state -> z = x@Wx1 + b1 (fp32, one-shot)
  gemm64_kernel<<<dim3(16, 4), 256, 0, stream>>>(inp, Wx1, zparts, E_DIM, GATES);
  gates_kernel<<<256, 256, 0, stream>>>(zparts, 4, b1, nullptr, h, c,
                                        (_Float16*)hpkA);  // slot 0 = h_0

  // Phase A: pure state recurrence. h_{t+1} = lstm(h_t); sampling never feeds back,
  // so we only compute/pack the hidden trajectory here (slots 1..31).
  for (int t = 0; t < T_STEPS; t++) {
    mfma_gemm<<<dim3(16, 8), 256, 0, stream>>>(
        (const half8*)(hpkA + (size_t)t * 65536), (const half8*)W2_pk,
        zparts, GATES);
    gates_kernel<<<256, 256, 0, stream>>>(
        zparts, 8, b2, c, h, c, (_Float16*)(hpkA + (size_t)(t + 1) * 65536));
  }

  // Phase B: ONE fused dispatch for all 31 logits GEMMs + sampling stage 1.
  // Wd_pk is streamed from HBM once (t fastest-varying -> 31 consecutive blocks
  // share each 1 MB column slice); the 254 MB logits tensor is never written.
  mfma_logits_fused<<<dim3(T_STEPS, NCHUNK), 256, 0, stream>>>(
      (const half8*)hpkA, (const half8*)Wd_pk, bd,
      pm, ps, pt2, pbest, plb, pbi);

  // Phase C: one batched stage-2 reduction for all (b, t)
  sample_stage2_batch<<<dim3(B_DIM, T_STEPS), 128, 0, stream>>>(
      pm, ps, pt2, pbest, plb, pbi, out);

  copy_kernel<<<256, 256, 0, stream>>>(h, out + 11904, B_DIM * H_DIM);
}

// Round 3
// 1541.249 us; speedup vs baseline: 1.2969x; 1.0303x over previous
//
#include <hip/hip_runtime.h>
#include <stdint.h>
#include <math.h>

// Problem constants
#define B_DIM 64
#define E_DIM 512
#define H_DIM 1024
#define V_DIM 32000
#define T_STEPS 31
#define GATES 4096          // 4*H
#define OUT_COLS 62         // 2*T
#define NCHUNK 125          // 32000 / 256
#define STOT 32             // K=1024 -> 32 k-steps of 32
#define NBLK (T_STEPS * NCHUNK)  // 3875 fused-logits blocks

// JAX >= 0.4.36 default: jax_threefry_partitionable = True
#define RNG_PARTITIONABLE 1

typedef _Float16 half8 __attribute__((ext_vector_type(8)));
typedef float floatx4 __attribute__((ext_vector_type(4)));

// ---------------- threefry2x32 (exact JAX reference) ----------------
__device__ __forceinline__ void tf_round(uint32_t& x0, uint32_t& x1, int r) {
  x0 += x1;
  x1 = (x1 << r) | (x1 >> (32 - r));
  x1 ^= x0;
}

__device__ __forceinline__ void threefry2x32(uint32_t k0, uint32_t k1,
                                             uint32_t& x0, uint32_t& x1) {
  uint32_t k2 = k0 ^ k1 ^ 0x1BD11BDAu;
  x0 += k0; x1 += k1;
  tf_round(x0,x1,13); tf_round(x0,x1,15); tf_round(x0,x1,26); tf_round(x0,x1,6);
  x0 += k1; x1 += k2 + 1u;
  tf_round(x0,x1,17); tf_round(x0,x1,29); tf_round(x0,x1,16); tf_round(x0,x1,24);
  x0 += k2; x1 += k0 + 2u;
  tf_round(x0,x1,13); tf_round(x0,x1,15); tf_round(x0,x1,26); tf_round(x0,x1,6);
  x0 += k0; x1 += k1 + 3u;
  tf_round(x0,x1,17); tf_round(x0,x1,29); tf_round(x0,x1,16); tf_round(x0,x1,24);
  x0 += k1; x1 += k2 + 4u;
  tf_round(x0,x1,13); tf_round(x0,x1,15); tf_round(x0,x1,26); tf_round(x0,x1,6);
  x0 += k2; x1 += k0 + 5u;
}

// ---------------- small utility kernels ----------------
__global__ void zero_kernel(float* __restrict__ o, int n) {
  int i = blockIdx.x * blockDim.x + threadIdx.x;
  if (i < n) o[i] = 0.0f;
}

__global__ void copy_kernel(const float* __restrict__ a, float* __restrict__ o, int n) {
  int i = blockIdx.x * blockDim.x + threadIdx.x;
  if (i < n) o[i] = a[i];
}

// ---------------- weight repack: fp32 (a [+ b]) -> f16 hi/lo MFMA B-fragments ----
__global__ __launch_bounds__(256)
void repack_w(const float* __restrict__ Wa, const float* __restrict__ Wb,
              _Float16* __restrict__ pk, int N) {
  int gw = blockIdx.x * 4 + (threadIdx.x >> 6);
  int total = (N >> 4) * STOT;
  if (gw >= total) return;
  int nt = gw >> 5, s = gw & 31;
  int lane = threadIdx.x & 63;
  int quad = lane >> 4, lm = lane & 15;
  int col = nt * 16 + lm;
  half8 hi, lo;
#pragma unroll
  for (int j = 0; j < 8; ++j) {
    int row = s * 32 + quad * 8 + j;
    float v = Wa[(size_t)row * N + col];
    if (Wb) v += Wb[(size_t)row * N + col];
    _Float16 h = (_Float16)v;
    hi[j] = h;
    lo[j] = (_Float16)(v - (float)h);
  }
  _Float16* o = pk + ((size_t)(nt * 32 + s) * 2) * 512 + lane * 8;
  *(half8*)o = hi;
  *(half8*)(o + 512) = lo;
}

// Fragment-load / MFMA macros for the recurrence GEMM (register A+B path).
#define LOAD_FRAGS(s_, A_, B_)                                              \
  {                                                                         \
    _Pragma("unroll")                                                       \
    for (int mt = 0; mt < 4; ++mt) {                                        \
      const half8* ap = Apk + ((size_t)(mt * 32 + (s_)) * 2) * 64 + lane;   \
      A_[mt][0] = ap[0];                                                    \
      A_[mt][1] = ap[64];                                                   \
    }                                                                       \
    _Pragma("unroll")                                                       \
    for (int nt = 0; nt < 4; ++nt) {                                        \
      const half8* bp =                                                     \
          Wpk + ((size_t)((nt0 + nt) * 32 + (s_)) * 2) * 64 + lane;         \
      B_[nt][0] = bp[0];                                                    \
      B_[nt][1] = bp[64];                                                   \
    }                                                                       \
  }

#define DO_MFMA(A_, B_)                                                     \
  {                                                                         \
    _Pragma("unroll")                                                       \
    for (int mt = 0; mt < 4; ++mt) {                                        \
      _Pragma("unroll")                                                     \
      for (int nt = 0; nt < 4; ++nt) {                                      \
        acc[mt][nt] = __builtin_amdgcn_mfma_f32_16x16x32_f16(               \
            A_[mt][0], B_[nt][0], acc[mt][nt], 0, 0, 0);                    \
        acc[mt][nt] = __builtin_amdgcn_mfma_f32_16x16x32_f16(               \
            A_[mt][1], B_[nt][0], acc[mt][nt], 0, 0, 0);                    \
        acc[mt][nt] = __builtin_amdgcn_mfma_f32_16x16x32_f16(               \
            A_[mt][0], B_[nt][1], acc[mt][nt], 0, 0, 0);                    \
      }                                                                     \
    }                                                                       \
  }

// ---------------- MFMA GEMM (k-split variant, used by the state recurrence) ----
__global__ __launch_bounds__(256, 1)
void mfma_gemm(const half8* __restrict__ Apk, const half8* __restrict__ Wpk,
               float* __restrict__ P, int N) {
  const int w = threadIdx.x >> 6;
  const int lane = threadIdx.x & 63;
  const int schunk = STOT / gridDim.y;
  const int s0 = blockIdx.y * schunk;
  const int send = s0 + schunk;
  const int nt0 = blockIdx.x * 16 + w * 4;

  floatx4 acc[4][4] = {};
  half8 a0[4][2], b0[4][2], a1[4][2], b1[4][2];

  LOAD_FRAGS(s0, a0, b0);
  for (int s = s0; s < send; s += 2) {
    LOAD_FRAGS(s + 1, a1, b1);
    DO_MFMA(a0, b0);
    if (s + 2 < send) LOAD_FRAGS(s + 2, a0, b0);
    DO_MFMA(a1, b1);
  }

  const int row0 = (lane >> 4) * 4;
  const int colb = blockIdx.x * 256 + w * 64 + (lane & 15);
  float* Pb = P + (size_t)blockIdx.y * 64 * N;
#pragma unroll
  for (int mt = 0; mt < 4; ++mt)
#pragma unroll
    for (int nt = 0; nt < 4; ++nt)
#pragma unroll
      for (int r = 0; r < 4; ++r)
        Pb[(size_t)(mt * 16 + row0 + r) * N + colb + nt * 16] = acc[mt][nt][r];
}
#undef LOAD_FRAGS
#undef DO_MFMA

// ---------------- fused logits GEMM + sampling stage 1 ----------------
// One dispatch for all t. 1D grid with bijective XCD swizzle (assumes block id
// round-robins XCDs): each XCD owns a contiguous range of (chunk, t) work with
// t fastest, so all 31 t-blocks of a vocab chunk run on ONE XCD and its 1 MB
// Wd slice is L2-hot after the first. A fragments (identical across the 4
// waves) are staged once per K-step into LDS via async global_load_lds
// (double-buffered), removing the 4x-redundant synchronous A loads.
__global__ __launch_bounds__(256, 1)
void mfma_logits_fused(const half8* __restrict__ hpkA, const half8* __restrict__ Wpk,
                       const float* __restrict__ bd,
                       float* __restrict__ pm, float* __restrict__ ps,
                       float* __restrict__ pt2, float* __restrict__ pbest,
                       float* __restrict__ plb, int* __restrict__ pbi) {
  // ----- XCD-aware bijective swizzle: 3875 = 8*484 + 3 (m204 form) -----
  const int p = blockIdx.x;
  const int x = p & 7, i = p >> 3;
  const int g = (x < 3 ? x * 485 : 1455 + (x - 3) * 484) + i;
  const int t = g % 31;
  const int chunk = g / 31;

  const int w = threadIdx.x >> 6;
  const int lane = threadIdx.x & 63;
  const int lm = lane & 15, q = lane >> 4;
  const _Float16* Ah = (const _Float16*)(hpkA + (size_t)(t + 1) * 16384);  // h_{t+1}
  const int nt0 = chunk * 16 + w * 4;

  __shared__ _Float16 A_lds[2][8][512];  // [buf][mt*2+half][frag bytes/2]

  floatx4 acc[4][4] = {};
  half8 a[4][2], b0[4][2], b1[4][2];

  // wave w stages both halves of A tile mt=w (1 KB each, lane*16B pattern)
#define STAGE_A(s_, buf_)                                                      \
  {                                                                            \
    const _Float16* sp = Ah + ((size_t)(w * 32 + (s_)) * 2) * 512 + lane * 8;  \
    __builtin_amdgcn_global_load_lds(                                          \
        (const __attribute__((address_space(1))) void*)sp,                     \
        (__attribute__((address_space(3))) void*)&A_lds[buf_][w * 2 + 0][0],   \
        16, 0, 0);                                                             \
    __builtin_amdgcn_global_load_lds(                                          \
        (const __attribute__((address_space(1))) void*)(sp + 512),             \
        (__attribute__((address_space(3))) void*)&A_lds[buf_][w * 2 + 1][0],   \
        16, 0, 0);                                                             \
  }

#define LOAD_B(s_, B_)                                                         \
  {                                                                            \
    _Pragma("unroll")                                                          \
    for (int nt = 0; nt < 4; ++nt) {                                           \
      const half8* bp =                                                        \
          Wpk + ((size_t)((nt0 + nt) * 32 + (s_)) * 2) * 64 + lane;            \
      B_[nt][0] = bp[0];                                                       \
      B_[nt][1] = bp[64];                                                      \
    }                                                                          \
  }

#define DS_READ_A(buf_)                                                        \
  {                                                                            \
    _Pragma("unroll")                                                          \
    for (int mt = 0; mt < 4; ++mt) {                                           \
      a[mt][0] = *(const half8*)&A_lds[buf_][mt * 2 + 0][lane * 8];            \
      a[mt][1] = *(const half8*)&A_lds[buf_][mt * 2 + 1][lane * 8];            \
    }                                                                          \
  }

#define DO_MFMA3(B_)                                                           \
  {                                                                            \
    _Pragma("unroll")                                                          \
    for (int mt = 0; mt < 4; ++mt) {                                           \
      _Pragma("unroll")                                                        \
      for (int nt = 0; nt < 4; ++nt) {                                         \
        acc[mt][nt] = __builtin_amdgcn_mfma_f32_16x16x32_f16(                  \
            a[mt][0], B_[nt][0], acc[mt][nt], 0, 0, 0);                        \
        acc[mt][nt] = __builtin_amdgcn_mfma_f32_16x16x32_f16(                  \
            a[mt][1], B_[nt][0], acc[mt][nt], 0, 0, 0);                        \
        acc[mt][nt] = __builtin_amdgcn_mfma_f32_16x16x32_f16(                  \
            a[mt][0], B_[nt][1], acc[mt][nt], 0, 0, 0);                        \
      }                                                                        \
    }                                                                          \
  }

  STAGE_A(0, 0);
  LOAD_B(0, b0);
  __syncthreads();  // drains stage(0) (vmcnt0 before s_barrier)

  for (int s = 0; s < STOT; s += 2) {
    STAGE_A(s + 1, 1);      // async into buf1 while buf0 is read
    LOAD_B(s + 1, b1);
    DS_READ_A(0);
    DO_MFMA3(b0);
    __syncthreads();        // buf1 staged + all waves done with buf0
    if (s + 2 < STOT) { STAGE_A(s + 2, 0); LOAD_B(s + 2, b0); }
    DS_READ_A(1);
    DO_MFMA3(b1);
    __syncthreads();
  }
#undef STAGE_A
#undef LOAD_B
#undef DS_READ_A
#undef DO_MFMA3

  // ---------- epilogue: bias + stage-1 partials ----------
  const int colb = chunk * 256 + w * 64 + lm;

  float bdv[4];
#pragma unroll
  for (int nt = 0; nt < 4; ++nt) bdv[nt] = bd[colb + nt * 16];
#pragma unroll
  for (int mt = 0; mt < 4; ++mt)
#pragma unroll
    for (int nt = 0; nt < 4; ++nt)
#pragma unroll
      for (int r = 0; r < 4; ++r) acc[mt][nt][r] += bdv[nt];

  __shared__ float redM[4][64];
  __shared__ float redS[4][64], redT[4][64], redBV[4][64], redBL[4][64];
  __shared__ int   redBI[4][64];

  // per-row max over this block's 256 cols
  float M[4][4];
#pragma unroll
  for (int mt = 0; mt < 4; ++mt) {
#pragma unroll
    for (int r = 0; r < 4; ++r) {
      float m = fmaxf(fmaxf(acc[mt][0][r], acc[mt][1][r]),
                      fmaxf(acc[mt][2][r], acc[mt][3][r]));
#pragma unroll
      for (int off = 1; off <= 8; off <<= 1) m = fmaxf(m, __shfl_xor(m, off));
      if (lm == 0) redM[w][mt * 16 + q * 4 + r] = m;
      M[mt][r] = m;
    }
  }
  __syncthreads();
#pragma unroll
  for (int mt = 0; mt < 4; ++mt)
#pragma unroll
    for (int r = 0; r < 4; ++r) {
      int b = mt * 16 + q * 4 + r;
      M[mt][r] = fmaxf(fmaxf(redM[0][b], redM[1][b]),
                       fmaxf(redM[2][b], redM[3][b]));
    }

  // threefry key for this t (uniform per block)
  uint32_t tk0 = 0u, tk1 = (uint32_t)t;
  threefry2x32(0u, 1234u, tk0, tk1);

#pragma unroll
  for (int mt = 0; mt < 4; ++mt) {
#pragma unroll
    for (int r = 0; r < 4; ++r) {
      const int b = mt * 16 + q * 4 + r;
      const float Mrow = M[mt][r];
      float s = 0.f, t2 = 0.f, bv = -INFINITY, bl = 0.f;
      int bi = 0x7fffffff;
#pragma unroll
      for (int nt = 0; nt < 4; ++nt) {
        float l = acc[mt][nt][r];
        int v = colb + nt * 16;
        float e = expf(l - Mrow);
        s += e;
        t2 += e * l;
        uint32_t j = (uint32_t)(b * V_DIM + v);
#if RNG_PARTITIONABLE
        uint32_t y0 = 0u, y1 = j;
        threefry2x32(tk0, tk1, y0, y1);
        uint32_t bits = y0 ^ y1;
#else
        const uint32_t half = (uint32_t)(B_DIM * V_DIM / 2);
        uint32_t y0, y1;
        if (j < half) { y0 = j; y1 = j + half; } else { y0 = j - half; y1 = j; }
        threefry2x32(tk0, tk1, y0, y1);
        uint32_t bits = (j < half) ? y0 : y1;
#endif
        float u = __uint_as_float((bits >> 9) | 0x3f800000u) - 1.0f;
        u = fmaxf(u, 1.17549435e-38f);
        float g2 = -logf(-logf(u));
        float val = l + g2;
        if (val > bv || (val == bv && v < bi)) { bv = val; bi = v; bl = l; }
      }
      // 16-lane xor reduce (sum / argmax)
#pragma unroll
      for (int off = 1; off <= 8; off <<= 1) {
        s  += __shfl_xor(s, off);
        t2 += __shfl_xor(t2, off);
        float ob = __shfl_xor(bv, off);
        int   oi = __shfl_xor(bi, off);
        float ol = __shfl_xor(bl, off);
        if (ob > bv || (ob == bv && oi < bi)) { bv = ob; bi = oi; bl = ol; }
      }
      if (lm == 0) {
        redS[w][b] = s; redT[w][b] = t2;
        redBV[w][b] = bv; redBI[w][b] = bi; redBL[w][b] = bl;
      }
    }
  }
  __syncthreads();
  // final cross-wave combine: wave 0, lane = row b
  if (w == 0) {
    int b = lane;
    float Mg = fmaxf(fmaxf(redM[0][b], redM[1][b]),
                     fmaxf(redM[2][b], redM[3][b]));
    float S  = redS[0][b] + redS[1][b] + redS[2][b] + redS[3][b];
    float T2 = redT[0][b] + redT[1][b] + redT[2][b] + redT[3][b];
    float Bv = redBV[0][b]; int BI = redBI[0][b]; float Bl = redBL[0][b];
#pragma unroll
    for (int ww = 1; ww < 4; ++ww) {
      if (redBV[ww][b] > Bv || (redBV[ww][b] == Bv && redBI[ww][b] < BI)) {
        Bv = redBV[ww][b]; BI = redBI[ww][b]; Bl = redBL[ww][b];
      }
    }
    size_t o = ((size_t)t * B_DIM + b) * NCHUNK + chunk;
    pm[o] = Mg; ps[o] = S; pt2[o] = T2; pbest[o] = Bv; plb[o] = Bl;
    pbi[o] = BI;
  }
}

// ---------------- fp32 GEMM (encoder only, one-shot) ----------------
__global__ __launch_bounds__(256, 2)
void gemm64_kernel(const float* __restrict__ A, const float* __restrict__ W,
                   float* __restrict__ P, int K, int N) {
  const int vt = blockIdx.x;
  const int ks = blockIdx.y;
  const int kchunk = K / gridDim.y;
  const int kbase = ks * kchunk;
  const int v0 = vt * 256;

  __shared__ float As[32][68];
  __shared__ float Ws[32][256];

  float acc[8][8];
#pragma unroll
  for (int i = 0; i < 8; i++)
#pragma unroll
    for (int j = 0; j < 8; j++) acc[i][j] = 0.0f;

  const int tid = threadIdx.x;
  const int cg4 = (tid & 31) * 4;
  const int rg4 = (tid >> 5) * 4;

  for (int k0 = kbase; k0 < kbase + kchunk; k0 += 32) {
    __syncthreads();
    {
      int b  = tid >> 3;
      int f4 = tid & 7;
      const float* Ab = A + (size_t)b * K + k0 + f4 * 4;
      float4 a0 = *(const float4*)Ab;
      float4 a1 = *(const float4*)(Ab + (size_t)32 * K);
      int kk0 = f4 * 4;
      As[kk0+0][b] = a0.x; As[kk0+1][b] = a0.y; As[kk0+2][b] = a0.z; As[kk0+3][b] = a0.w;
      As[kk0+0][b+32] = a1.x; As[kk0+1][b+32] = a1.y; As[kk0+2][b+32] = a1.z; As[kk0+3][b+32] = a1.w;
    }
#pragma unroll
    for (int p = 0; p < 8; p++) {
      int idx = tid + p * 256;
      int row = idx >> 6, c4 = idx & 63;
      *(float4*)&Ws[row][c4 * 4] =
          *(const float4*)(W + (size_t)(k0 + row) * N + v0 + c4 * 4);
    }
    __syncthreads();

#pragma unroll 8
    for (int kk = 0; kk < 32; kk++) {
      float4 a0 = *(const float4*)&As[kk][rg4];
      float4 a1 = *(const float4*)&As[kk][32 + rg4];
      float4 w0 = *(const float4*)&Ws[kk][cg4];
      float4 w1 = *(const float4*)&Ws[kk][128 + cg4];
      float av[8] = {a0.x, a0.y, a0.z, a0.w, a1.x, a1.y, a1.z, a1.w};
      float wv[8] = {w0.x, w0.y, w0.z, w0.w, w1.x, w1.y, w1.z, w1.w};
#pragma unroll
      for (int i = 0; i < 8; i++)
#pragma unroll
        for (int j = 0; j < 8; j++)
          acc[i][j] = fmaf(av[i], wv[j], acc[i][j]);
    }
  }

  const size_t base = (size_t)ks * 64 * N;
#pragma unroll
  for (int i = 0; i < 8; i++) {
    int row = (i < 4) ? (rg4 + i) : (32 + rg4 + i - 4);
    float4 s0 = make_float4(acc[i][0], acc[i][1], acc[i][2], acc[i][3]);
    float4 s1 = make_float4(acc[i][4], acc[i][5], acc[i][6], acc[i][7]);
    *(float4*)(P + base + (size_t)row * N + v0 + cg4) = s0;
    *(float4*)(P + base + (size_t)row * N + v0 + 128 + cg4) = s1;
  }
}

// ---------------- LSTM gate fusion + A-fragment pack ----------------
__global__ void gates_kernel(const float* __restrict__ zp, int ksplit,
                             const float* __restrict__ bias,
                             const float* __restrict__ c_in,
                             float* __restrict__ h_out, float* __restrict__ c_out,
                             _Float16* __restrict__ hpk) {
  int tid = blockIdx.x * blockDim.x + threadIdx.x;
  if (tid >= B_DIM * H_DIM) return;
  int b = tid >> 10, j = tid & 1023;
  float zi = bias[j], zf = bias[j + 1024], zg = bias[j + 2048], zo = bias[j + 3072];
  const float* Pb = zp + (size_t)b * GATES;
  for (int p = 0; p < ksplit; p++) {
    const float* P = Pb + (size_t)p * B_DIM * GATES;
    zi += P[j]; zf += P[j + 1024]; zg += P[j + 2048]; zo += P[j + 3072];
  }
  float cp = c_in ? c_in[tid] : 0.0f;
  float si = 1.0f / (1.0f + expf(-zi));
  float sf = 1.0f / (1.0f + expf(-zf));
  float so = 1.0f / (1.0f + expf(-zo));
  float c = sf * cp + si * zg;
  c_out[tid] = c;
  float hv = so * c;
  h_out[tid] = hv;

  int mt = b >> 4, lm = b & 15;
  int s = j >> 5, quad = (j >> 3) & 3, jj = j & 7;
  size_t off = ((size_t)(mt * 32 + s) * 2) * 512 + (size_t)(quad * 16 + lm) * 8 + jj;
  _Float16 hh = (_Float16)hv;
  hpk[off] = hh;
  hpk[off + 512] = (_Float16)(hv - (float)hh);
}

// ---------------- batched sampling stage 2: reduce 125 chunks per (b,t) ---------
__global__ __launch_bounds__(128)
void sample_stage2_batch(const float* __restrict__ pm, const float* __restrict__ ps,
                         const float* __restrict__ pt2, const float* __restrict__ pbest,
                         const float* __restrict__ plb, const int* __restrict__ pbi,
                         float* __restrict__ out) {
  const int b = blockIdx.x;
  const int t = blockIdx.y;
  const int tid = threadIdx.x;
  const size_t base = ((size_t)t * B_DIM + b) * NCHUNK;
  const bool valid = tid < NCHUNK;

  float m   = valid ? pm[base + tid]    : -INFINITY;
  float bv  = valid ? pbest[base + tid] : -INFINITY;
  float blv = valid ? plb[base + tid]   : 0.0f;
  int   bi  = valid ? pbi[base + tid]   : 0x7fffffff;

  float M = m;
  for (int off = 32; off > 0; off >>= 1) M = fmaxf(M, __shfl_down(M, off));
  __shared__ float sM[2];
  int wave = tid >> 6, lane = tid & 63;
  if (lane == 0) sM[wave] = M;
  __syncthreads();
  const float Mg = fmaxf(sM[0], sM[1]);

  float sc = valid ? expf(m - Mg) : 0.0f;
  float s  = valid ? ps[base + tid]  * sc : 0.0f;
  float t2 = valid ? pt2[base + tid] * sc : 0.0f;
  for (int off = 32; off > 0; off >>= 1) {
    s  += __shfl_down(s, off);
    t2 += __shfl_down(t2, off);
    float ob = __shfl_down(bv, off);
    int   oi = __shfl_down(bi, off);
    float ol = __shfl_down(blv, off);
    if (ob > bv || (ob == bv && oi < bi)) { bv = ob; bi = oi; blv = ol; }
  }
  __shared__ float sS[2], sT[2], sB[2], sL[2];
  __shared__ int sI[2];
  if (lane == 0) { sS[wave] = s; sT[wave] = t2; sB[wave] = bv; sI[wave] = bi; sL[wave] = blv; }
  __syncthreads();
  if (tid == 0) {
    float S = sS[0] + sS[1], T2 = sT[0] + sT[1];
    float Bv = sB[0], Bl = sL[0]; int BI = sI[0];
    if (sB[1] > Bv || (sB[1] == Bv && sI[1] < BI)) { Bv = sB[1]; BI = sI[1]; Bl = sL[1]; }
    float lse = Mg + logf(S);
    out[(size_t)b * OUT_COLS + t]        = (float)BI;    // msg
    out[3968 + (size_t)b * OUT_COLS + t] = Bl - lse;     // log_prob
    out[7936 + (size_t)b * OUT_COLS + t] = lse - T2 / S; // entropy
  }
}

// ---------------- launcher ----------------
extern "C" void kernel_launch(void* const* d_in, const int* in_sizes, int n_in,
                              void* d_out, int out_size, void* d_ws, size_t ws_size,
                              hipStream_t stream) {
  const float* inp = (const float*)d_in[0];
  const float* Wx1 = (const float*)d_in[1];
  // d_in[2] = Wh1: unused (encoder initial h == 0)
  const float* b1  = (const float*)d_in[3];
  const float* Wx2 = (const float*)d_in[4];
  const float* Wh2 = (const float*)d_in[5];
  const float* b2  = (const float*)d_in[6];
  const float* Wd  = (const float*)d_in[7];
  const float* bd  = (const float*)d_in[8];
  float* out = (float*)d_out;

  float* ws = (float*)d_ws;
  float* Wd_pk  = ws;                    // 32,768,000 floats (131 MB f16 hi/lo)
  float* W2_pk  = Wd_pk + 32768000;      //  4,194,304
  float* hpkA   = W2_pk + 4194304;       //  2,097,152 (32 slots x 65,536: h_0..h_31 packed)
  float* zparts = hpkA + 2097152;        //  2,097,152 (8 k-split parts; partials alias)
  float* h      = zparts + 2097152;      //     65,536
  float* c      = h + 65536;             //     65,536

  // sampling partials alias zparts (dead after the recurrence phase)
  float* pm    = zparts;
  float* ps    = zparts + 248000;
  float* pt2   = zparts + 496000;
  float* pbest = zparts + 744000;
  float* plb   = zparts + 992000;
  int*   pbi   = (int*)(zparts + 1240000);

  // one-time: repack Wd and (Wx2+Wh2) into f16 hi/lo MFMA fragments
  repack_w<<<16000, 256, 0, stream>>>(Wd, nullptr, (_Float16*)Wd_pk, V_DIM);
  repack_w<<<2048, 256, 0, stream>>>(Wx2, Wh2, (_Float16*)W2_pk, GATES);
  zero_kernel<<<47, 256, 0, stream>>>(out, 11904);

  // encoder: single step, zero initial state -> z = x@Wx1 + b1 (fp32, one-shot)
  gemm64_kernel<<<dim3(16, 4), 256, 0, stream>>>(inp, Wx1, zparts, E_DIM, GATES);
  gates_kernel<<<256, 256, 0, stream>>>(zparts, 4, b1, nullptr, h, c,
                                        (_Float16*)hpkA);  // slot 0 = h_0

  // Phase A: pure state recurrence (sampling never feeds back): slots 1..31.
  for (int t = 0; t < T_STEPS; t++) {
    mfma_gemm<<<dim3(16, 8), 256, 0, stream>>>(
        (const half8*)(hpkA + (size_t)t * 65536), (const half8*)W2_pk,
        zparts, GATES);
    gates_kernel<<<256, 256, 0, stream>>>(
        zparts, 8, b2, c, h, c, (_Float16*)(hpkA + (size_t)(t + 1) * 65536));
  }

  // Phase B: ONE fused dispatch for all 31 logits GEMMs + sampling stage 1.
  // 1D grid, XCD-swizzled inside the kernel.
  mfma_logits_fused<<<dim3(NBLK), 256, 0, stream>>>(
      (const half8*)hpkA, (const half8*)Wd_pk, bd,
      pm, ps, pt2, pbest, plb, pbi);

  // Phase C: one batched stage-2 reduction for all (b, t)
  sample_stage2_batch<<<dim3(B_DIM, T_STEPS), 128, 0, stream>>>(
      pm, ps, pt2, pbest, plb, pbi, out);

  copy_kernel<<<256, 256, 0, stream>>>(h, out + 11904, B_DIM * H_DIM);
}

// Round 4
// 1352.709 us; speedup vs baseline: 1.4777x; 1.1394x over previous
//
#include <hip/hip_runtime.h>
#include <stdint.h>
#include <math.h>

// Problem constants
#define B_DIM 64
#define E_DIM 512
#define H_DIM 1024
#define V_DIM 32000
#define T_STEPS 31
#define GATES 4096          // 4*H
#define OUT_COLS 62         // 2*T
#define NCHUNK 125          // 32000 / 256
#define STOT 32             // K=1024 -> 32 k-steps of 32
#define NTPAIR 16           // ceil(31/2) t-pairs
#define NBLK2 (NTPAIR * NCHUNK)  // 2000 fused-logits blocks (= 8 * 250)

// JAX >= 0.4.36 default: jax_threefry_partitionable = True
#define RNG_PARTITIONABLE 1

typedef _Float16 half8 __attribute__((ext_vector_type(8)));
typedef float floatx4 __attribute__((ext_vector_type(4)));

// ---------------- threefry2x32 (exact JAX reference) ----------------
__device__ __forceinline__ void tf_round(uint32_t& x0, uint32_t& x1, int r) {
  x0 += x1;
  x1 = (x1 << r) | (x1 >> (32 - r));
  x1 ^= x0;
}

__device__ __forceinline__ void threefry2x32(uint32_t k0, uint32_t k1,
                                             uint32_t& x0, uint32_t& x1) {
  uint32_t k2 = k0 ^ k1 ^ 0x1BD11BDAu;
  x0 += k0; x1 += k1;
  tf_round(x0,x1,13); tf_round(x0,x1,15); tf_round(x0,x1,26); tf_round(x0,x1,6);
  x0 += k1; x1 += k2 + 1u;
  tf_round(x0,x1,17); tf_round(x0,x1,29); tf_round(x0,x1,16); tf_round(x0,x1,24);
  x0 += k2; x1 += k0 + 2u;
  tf_round(x0,x1,13); tf_round(x0,x1,15); tf_round(x0,x1,26); tf_round(x0,x1,6);
  x0 += k0; x1 += k1 + 3u;
  tf_round(x0,x1,17); tf_round(x0,x1,29); tf_round(x0,x1,16); tf_round(x0,x1,24);
  x0 += k1; x1 += k2 + 4u;
  tf_round(x0,x1,13); tf_round(x0,x1,15); tf_round(x0,x1,26); tf_round(x0,x1,6);
  x0 += k2; x1 += k0 + 5u;
}

// ---------------- small utility kernels ----------------
__global__ void zero_kernel(float* __restrict__ o, int n) {
  int i = blockIdx.x * blockDim.x + threadIdx.x;
  if (i < n) o[i] = 0.0f;
}

__global__ void copy_kernel(const float* __restrict__ a, float* __restrict__ o, int n) {
  int i = blockIdx.x * blockDim.x + threadIdx.x;
  if (i < n) o[i] = a[i];
}

// ---------------- weight repack: fp32 (a [+ b]) -> f16 hi/lo MFMA B-fragments ----
__global__ __launch_bounds__(256)
void repack_w(const float* __restrict__ Wa, const float* __restrict__ Wb,
              _Float16* __restrict__ pk, int N) {
  int gw = blockIdx.x * 4 + (threadIdx.x >> 6);
  int total = (N >> 4) * STOT;
  if (gw >= total) return;
  int nt = gw >> 5, s = gw & 31;
  int lane = threadIdx.x & 63;
  int quad = lane >> 4, lm = lane & 15;
  int col = nt * 16 + lm;
  half8 hi, lo;
#pragma unroll
  for (int j = 0; j < 8; ++j) {
    int row = s * 32 + quad * 8 + j;
    float v = Wa[(size_t)row * N + col];
    if (Wb) v += Wb[(size_t)row * N + col];
    _Float16 h = (_Float16)v;
    hi[j] = h;
    lo[j] = (_Float16)(v - (float)h);
  }
  _Float16* o = pk + ((size_t)(nt * 32 + s) * 2) * 512 + lane * 8;
  *(half8*)o = hi;
  *(half8*)(o + 512) = lo;
}

// Fragment-load / MFMA macros (register A+B path).
#define LOAD_FRAGS(s_, A_, B_)                                              \
  {                                                                         \
    _Pragma("unroll")                                                       \
    for (int mt = 0; mt < 4; ++mt) {                                        \
      const half8* ap = Apk + ((size_t)(mt * 32 + (s_)) * 2) * 64 + lane;   \
      A_[mt][0] = ap[0];                                                    \
      A_[mt][1] = ap[64];                                                   \
    }                                                                       \
    _Pragma("unroll")                                                       \
    for (int nt = 0; nt < 4; ++nt) {                                        \
      const half8* bp =                                                     \
          Wpk + ((size_t)((nt0 + nt) * 32 + (s_)) * 2) * 64 + lane;         \
      B_[nt][0] = bp[0];                                                    \
      B_[nt][1] = bp[64];                                                   \
    }                                                                       \
  }

#define DO_MFMA(A_, B_)                                                     \
  {                                                                         \
    _Pragma("unroll")                                                       \
    for (int mt = 0; mt < 4; ++mt) {                                        \
      _Pragma("unroll")                                                     \
      for (int nt = 0; nt < 4; ++nt) {                                      \
        acc[mt][nt] = __builtin_amdgcn_mfma_f32_16x16x32_f16(               \
            A_[mt][0], B_[nt][0], acc[mt][nt], 0, 0, 0);                    \
        acc[mt][nt] = __builtin_amdgcn_mfma_f32_16x16x32_f16(               \
            A_[mt][1], B_[nt][0], acc[mt][nt], 0, 0, 0);                    \
        acc[mt][nt] = __builtin_amdgcn_mfma_f32_16x16x32_f16(               \
            A_[mt][0], B_[nt][1], acc[mt][nt], 0, 0, 0);                    \
      }                                                                     \
    }                                                                       \
  }

// ---------------- MFMA GEMM (k-split variant, used by the state recurrence) ----
__global__ __launch_bounds__(256, 1)
void mfma_gemm(const half8* __restrict__ Apk, const half8* __restrict__ Wpk,
               float* __restrict__ P, int N) {
  const int w = threadIdx.x >> 6;
  const int lane = threadIdx.x & 63;
  const int schunk = STOT / gridDim.y;
  const int s0 = blockIdx.y * schunk;
  const int send = s0 + schunk;
  const int nt0 = blockIdx.x * 16 + w * 4;

  floatx4 acc[4][4] = {};
  half8 a0[4][2], b0[4][2], a1[4][2], b1[4][2];

  LOAD_FRAGS(s0, a0, b0);
  for (int s = s0; s < send; s += 2) {
    LOAD_FRAGS(s + 1, a1, b1);
    DO_MFMA(a0, b0);
    if (s + 2 < send) LOAD_FRAGS(s + 2, a0, b0);
    DO_MFMA(a1, b1);
  }

  const int row0 = (lane >> 4) * 4;
  const int colb = blockIdx.x * 256 + w * 64 + (lane & 15);
  float* Pb = P + (size_t)blockIdx.y * 64 * N;
#pragma unroll
  for (int mt = 0; mt < 4; ++mt)
#pragma unroll
    for (int nt = 0; nt < 4; ++nt)
#pragma unroll
      for (int r = 0; r < 4; ++r)
        Pb[(size_t)(mt * 16 + row0 + r) * N + colb + nt * 16] = acc[mt][nt][r];
}

// ---------------- fused logits GEMM + sampling stage 1 ----------------
// One dispatch for all t. 512-thread blocks: waves 0-3 handle t = 2*tpair,
// waves 4-7 handle t = 2*tpair+1 (same vocab chunk -> B fragments shared via
// L1/L2). Barrier-free register-double-buffered main loop. 1D grid with exact
// bijective XCD swizzle (2000 = 8 x 250): all 16 t-pair blocks of a chunk run
// on one XCD so its 1 MB Wd slice is L2-hot after first touch.
// Epilogue uses fast __expf/__logf (v_exp/v_log) - libm transcendentals were
// the round-3 bottleneck (~25-40k VALU-cyc/wave, 3-5x the MFMA work).
__global__ __launch_bounds__(512, 2)
void mfma_logits_fused(const half8* __restrict__ hpkA, const half8* __restrict__ Wpk,
                       const float* __restrict__ bd,
                       float* __restrict__ pm, float* __restrict__ ps,
                       float* __restrict__ pt2, float* __restrict__ pbest,
                       float* __restrict__ plb, int* __restrict__ pbi) {
  // ----- XCD-aware bijective swizzle: 2000 = 8 * 250 -----
  const int p = blockIdx.x;
  const int g = (p & 7) * 250 + (p >> 3);
  const int tpair = g & 15;
  const int chunk = g >> 4;

  const int tid = threadIdx.x;
  const int w4 = tid >> 6;      // 0..7
  const int th = w4 >> 2;       // t-half (0/1)
  const int w  = w4 & 3;        // wave within t-half
  const int lane = tid & 63;
  const int lm = lane & 15, q = lane >> 4;
  const int t = tpair * 2 + th;
  const bool active = (t < T_STEPS);
  const int nt0 = chunk * 16 + w * 4;

  floatx4 acc[4][4] = {};

  if (active) {
    const half8* Apk = hpkA + (size_t)(t + 1) * 16384;  // h_{t+1} slot
    half8 a0[4][2], b0[4][2], a1[4][2], b1[4][2];

    LOAD_FRAGS(0, a0, b0);
    for (int s = 0; s < STOT; s += 2) {
      LOAD_FRAGS(s + 1, a1, b1);
      DO_MFMA(a0, b0);
      if (s + 2 < STOT) LOAD_FRAGS(s + 2, a0, b0);
      DO_MFMA(a1, b1);
    }
  }

  // ---------- epilogue: bias + stage-1 partials ----------
  __shared__ float redM[2][4][64];
  __shared__ float redS[2][4][64], redT[2][4][64], redBV[2][4][64], redBL[2][4][64];
  __shared__ int   redBI[2][4][64];

  const int colb = chunk * 256 + w * 64 + lm;
  float M[4][4];

  if (active) {
    float bdv[4];
#pragma unroll
    for (int nt = 0; nt < 4; ++nt) bdv[nt] = bd[colb + nt * 16];
#pragma unroll
    for (int mt = 0; mt < 4; ++mt)
#pragma unroll
      for (int nt = 0; nt < 4; ++nt)
#pragma unroll
        for (int r = 0; r < 4; ++r) acc[mt][nt][r] += bdv[nt];

    // per-row max over this block's 256 cols (in-lane 4, 16-lane xor tree)
#pragma unroll
    for (int mt = 0; mt < 4; ++mt) {
#pragma unroll
      for (int r = 0; r < 4; ++r) {
        float m = fmaxf(fmaxf(acc[mt][0][r], acc[mt][1][r]),
                        fmaxf(acc[mt][2][r], acc[mt][3][r]));
#pragma unroll
        for (int off = 1; off <= 8; off <<= 1) m = fmaxf(m, __shfl_xor(m, off));
        if (lm == 0) redM[th][w][mt * 16 + q * 4 + r] = m;
      }
    }
  }
  __syncthreads();

  if (active) {
#pragma unroll
    for (int mt = 0; mt < 4; ++mt)
#pragma unroll
      for (int r = 0; r < 4; ++r) {
        int b = mt * 16 + q * 4 + r;
        M[mt][r] = fmaxf(fmaxf(redM[th][0][b], redM[th][1][b]),
                         fmaxf(redM[th][2][b], redM[th][3][b]));
      }

    // threefry key for this t (uniform per t-half)
    uint32_t tk0 = 0u, tk1 = (uint32_t)t;
    threefry2x32(0u, 1234u, tk0, tk1);

#pragma unroll
    for (int mt = 0; mt < 4; ++mt) {
#pragma unroll
      for (int r = 0; r < 4; ++r) {
        const int b = mt * 16 + q * 4 + r;
        const float Mrow = M[mt][r];
        float s = 0.f, t2 = 0.f, bv = -INFINITY, bl = 0.f;
        int bi = 0x7fffffff;
#pragma unroll
        for (int nt = 0; nt < 4; ++nt) {
          float l = acc[mt][nt][r];
          int v = colb + nt * 16;
          float e = __expf(l - Mrow);   // fast v_exp: ~1e-7 rel, invisible vs 1.5e-5 GEMM residual
          s += e;
          t2 += e * l;
          uint32_t j = (uint32_t)(b * V_DIM + v);
#if RNG_PARTITIONABLE
          uint32_t y0 = 0u, y1 = j;
          threefry2x32(tk0, tk1, y0, y1);
          uint32_t bits = y0 ^ y1;
#else
          const uint32_t half = (uint32_t)(B_DIM * V_DIM / 2);
          uint32_t y0, y1;
          if (j < half) { y0 = j; y1 = j + half; } else { y0 = j - half; y1 = j; }
          threefry2x32(tk0, tk1, y0, y1);
          uint32_t bits = (j < half) ? y0 : y1;
#endif
          float u = __uint_as_float((bits >> 9) | 0x3f800000u) - 1.0f;
          u = fmaxf(u, 1.17549435e-38f);
          // gumbel steers only the argmax; fast v_log ULP noise is same risk
          // class as XLA-vs-libm differences already present
          float g2 = -__logf(-__logf(u));
          float val = l + g2;
          if (val > bv || (val == bv && v < bi)) { bv = val; bi = v; bl = l; }
        }
        // 16-lane xor reduce (sum / argmax)
#pragma unroll
        for (int off = 1; off <= 8; off <<= 1) {
          s  += __shfl_xor(s, off);
          t2 += __shfl_xor(t2, off);
          float ob = __shfl_xor(bv, off);
          int   oi = __shfl_xor(bi, off);
          float ol = __shfl_xor(bl, off);
          if (ob > bv || (ob == bv && oi < bi)) { bv = ob; bi = oi; bl = ol; }
        }
        if (lm == 0) {
          redS[th][w][b] = s; redT[th][w][b] = t2;
          redBV[th][w][b] = bv; redBI[th][w][b] = bi; redBL[th][w][b] = bl;
        }
      }
    }
  }
  __syncthreads();

  // final cross-wave combine: wave w==0 of each t-half, lane = row b
  if (active && w == 0) {
    int b = lane;
    float Mg = fmaxf(fmaxf(redM[th][0][b], redM[th][1][b]),
                     fmaxf(redM[th][2][b], redM[th][3][b]));
    float S  = redS[th][0][b] + redS[th][1][b] + redS[th][2][b] + redS[th][3][b];
    float T2 = redT[th][0][b] + redT[th][1][b] + redT[th][2][b] + redT[th][3][b];
    float Bv = redBV[th][0][b]; int BI = redBI[th][0][b]; float Bl = redBL[th][0][b];
#pragma unroll
    for (int ww = 1; ww < 4; ++ww) {
      if (redBV[th][ww][b] > Bv || (redBV[th][ww][b] == Bv && redBI[th][ww][b] < BI)) {
        Bv = redBV[th][ww][b]; BI = redBI[th][ww][b]; Bl = redBL[th][ww][b];
      }
    }
    size_t o = ((size_t)t * B_DIM + b) * NCHUNK + chunk;
    pm[o] = Mg; ps[o] = S; pt2[o] = T2; pbest[o] = Bv; plb[o] = Bl;
    pbi[o] = BI;
  }
}
#undef LOAD_FRAGS
#undef DO_MFMA

// ---------------- fp32 GEMM (encoder only, one-shot) ----------------
__global__ __launch_bounds__(256, 2)
void gemm64_kernel(const float* __restrict__ A, const float* __restrict__ W,
                   float* __restrict__ P, int K, int N) {
  const int vt = blockIdx.x;
  const int ks = blockIdx.y;
  const int kchunk = K / gridDim.y;
  const int kbase = ks * kchunk;
  const int v0 = vt * 256;

  __shared__ float As[32][68];
  __shared__ float Ws[32][256];

  float acc[8][8];
#pragma unroll
  for (int i = 0; i < 8; i++)
#pragma unroll
    for (int j = 0; j < 8; j++) acc[i][j] = 0.0f;

  const int tid = threadIdx.x;
  const int cg4 = (tid & 31) * 4;
  const int rg4 = (tid >> 5) * 4;

  for (int k0 = kbase; k0 < kbase + kchunk; k0 += 32) {
    __syncthreads();
    {
      int b  = tid >> 3;
      int f4 = tid & 7;
      const float* Ab = A + (size_t)b * K + k0 + f4 * 4;
      float4 a0 = *(const float4*)Ab;
      float4 a1 = *(const float4*)(Ab + (size_t)32 * K);
      int kk0 = f4 * 4;
      As[kk0+0][b] = a0.x; As[kk0+1][b] = a0.y; As[kk0+2][b] = a0.z; As[kk0+3][b] = a0.w;
      As[kk0+0][b+32] = a1.x; As[kk0+1][b+32] = a1.y; As[kk0+2][b+32] = a1.z; As[kk0+3][b+32] = a1.w;
    }
#pragma unroll
    for (int p = 0; p < 8; p++) {
      int idx = tid + p * 256;
      int row = idx >> 6, c4 = idx & 63;
      *(float4*)&Ws[row][c4 * 4] =
          *(const float4*)(W + (size_t)(k0 + row) * N + v0 + c4 * 4);
    }
    __syncthreads();

#pragma unroll 8
    for (int kk = 0; kk < 32; kk++) {
      float4 a0 = *(const float4*)&As[kk][rg4];
      float4 a1 = *(const float4*)&As[kk][32 + rg4];
      float4 w0 = *(const float4*)&Ws[kk][cg4];
      float4 w1 = *(const float4*)&Ws[kk][128 + cg4];
      float av[8] = {a0.x, a0.y, a0.z, a0.w, a1.x, a1.y, a1.z, a1.w};
      float wv[8] = {w0.x, w0.y, w0.z, w0.w, w1.x, w1.y, w1.z, w1.w};
#pragma unroll
      for (int i = 0; i < 8; i++)
#pragma unroll
        for (int j = 0; j < 8; j++)
          acc[i][j] = fmaf(av[i], wv[j], acc[i][j]);
    }
  }

  const size_t base = (size_t)ks * 64 * N;
#pragma unroll
  for (int i = 0; i < 8; i++) {
    int row = (i < 4) ? (rg4 + i) : (32 + rg4 + i - 4);
    float4 s0 = make_float4(acc[i][0], acc[i][1], acc[i][2], acc[i][3]);
    float4 s1 = make_float4(acc[i][4], acc[i][5], acc[i][6], acc[i][7]);
    *(float4*)(P + base + (size_t)row * N + v0 + cg4) = s0;
    *(float4*)(P + base + (size_t)row * N + v0 + 128 + cg4) = s1;
  }
}

// ---------------- LSTM gate fusion + A-fragment pack ----------------
__global__ void gates_kernel(const float* __restrict__ zp, int ksplit,
                             const float* __restrict__ bias,
                             const float* __restrict__ c_in,
                             float* __restrict__ h_out, float* __restrict__ c_out,
                             _Float16* __restrict__ hpk) {
  int tid = blockIdx.x * blockDim.x + threadIdx.x;
  if (tid >= B_DIM * H_DIM) return;
  int b = tid >> 10, j = tid & 1023;
  float zi = bias[j], zf = bias[j + 1024], zg = bias[j + 2048], zo = bias[j + 3072];
  const float* Pb = zp + (size_t)b * GATES;
  for (int p = 0; p < ksplit; p++) {
    const float* P = Pb + (size_t)p * B_DIM * GATES;
    zi += P[j]; zf += P[j + 1024]; zg += P[j + 2048]; zo += P[j + 3072];
  }
  float cp = c_in ? c_in[tid] : 0.0f;
  float si = 1.0f / (1.0f + expf(-zi));
  float sf = 1.0f / (1.0f + expf(-zf));
  float so = 1.0f / (1.0f + expf(-zo));
  float c = sf * cp + si * zg;
  c_out[tid] = c;
  float hv = so * c;
  h_out[tid] = hv;

  int mt = b >> 4, lm = b & 15;
  int s = j >> 5, quad = (j >> 3) & 3, jj = j & 7;
  size_t off = ((size_t)(mt * 32 + s) * 2) * 512 + (size_t)(quad * 16 + lm) * 8 + jj;
  _Float16 hh = (_Float16)hv;
  hpk[off] = hh;
  hpk[off + 512] = (_Float16)(hv - (float)hh);
}

// ---------------- batched sampling stage 2: reduce 125 chunks per (b,t) ---------
__global__ __launch_bounds__(128)
void sample_stage2_batch(const float* __restrict__ pm, const float* __restrict__ ps,
                         const float* __restrict__ pt2, const float* __restrict__ pbest,
                         const float* __restrict__ plb, const int* __restrict__ pbi,
                         float* __restrict__ out) {
  const int b = blockIdx.x;
  const int t = blockIdx.y;
  const int tid = threadIdx.x;
  const size_t base = ((size_t)t * B_DIM + b) * NCHUNK;
  const bool valid = tid < NCHUNK;

  float m   = valid ? pm[base + tid]    : -INFINITY;
  float bv  = valid ? pbest[base + tid] : -INFINITY;
  float blv = valid ? plb[base + tid]   : 0.0f;
  int   bi  = valid ? pbi[base + tid]   : 0x7fffffff;

  float M = m;
  for (int off = 32; off > 0; off >>= 1) M = fmaxf(M, __shfl_down(M, off));
  __shared__ float sM[2];
  int wave = tid >> 6, lane = tid & 63;
  if (lane == 0) sM[wave] = M;
  __syncthreads();
  const float Mg = fmaxf(sM[0], sM[1]);

  float sc = valid ? expf(m - Mg) : 0.0f;
  float s  = valid ? ps[base + tid]  * sc : 0.0f;
  float t2 = valid ? pt2[base + tid] * sc : 0.0f;
  for (int off = 32; off > 0; off >>= 1) {
    s  += __shfl_down(s, off);
    t2 += __shfl_down(t2, off);
    float ob = __shfl_down(bv, off);
    int   oi = __shfl_down(bi, off);
    float ol = __shfl_down(blv, off);
    if (ob > bv || (ob == bv && oi < bi)) { bv = ob; bi = oi; blv = ol; }
  }
  __shared__ float sS[2], sT[2], sB[2], sL[2];
  __shared__ int sI[2];
  if (lane == 0) { sS[wave] = s; sT[wave] = t2; sB[wave] = bv; sI[wave] = bi; sL[wave] = blv; }
  __syncthreads();
  if (tid == 0) {
    float S = sS[0] + sS[1], T2 = sT[0] + sT[1];
    float Bv = sB[0], Bl = sL[0]; int BI = sI[0];
    if (sB[1] > Bv || (sB[1] == Bv && sI[1] < BI)) { Bv = sB[1]; BI = sI[1]; Bl = sL[1]; }
    float lse = Mg + logf(S);
    out[(size_t)b * OUT_COLS + t]        = (float)BI;    // msg
    out[3968 + (size_t)b * OUT_COLS + t] = Bl - lse;     // log_prob
    out[7936 + (size_t)b * OUT_COLS + t] = lse - T2 / S; // entropy
  }
}

// ---------------- launcher ----------------
extern "C" void kernel_launch(void* const* d_in, const int* in_sizes, int n_in,
                              void* d_out, int out_size, void* d_ws, size_t ws_size,
                              hipStream_t stream) {
  const float* inp = (const float*)d_in[0];
  const float* Wx1 = (const float*)d_in[1];
  // d_in[2] = Wh1: unused (encoder initial h == 0)
  const float* b1  = (const float*)d_in[3];
  const float* Wx2 = (const float*)d_in[4];
  const float* Wh2 = (const float*)d_in[5];
  const float* b2  = (const float*)d_in[6];
  const float* Wd  = (const float*)d_in[7];
  const float* bd  = (const float*)d_in[8];
  float* out = (float*)d_out;

  float* ws = (float*)d_ws;
  float* Wd_pk  = ws;                    // 32,768,000 floats (131 MB f16 hi/lo)
  float* W2_pk  = Wd_pk + 32768000;      //  4,194,304
  float* hpkA   = W2_pk + 4194304;       //  2,097,152 (32 slots x 65,536: h_0..h_31 packed)
  float* zparts = hpkA + 2097152;        //  2,097,152 (8 k-split parts; partials alias)
  float* h      = zparts + 2097152;      //     65,536
  float* c      = h + 65536;             //     65,536

  // sampling partials alias zparts (dead after the recurrence phase)
  float* pm    = zparts;
  float* ps    = zparts + 248000;
  float* pt2   = zparts + 496000;
  float* pbest = zparts + 744000;
  float* plb   = zparts + 992000;
  int*   pbi   = (int*)(zparts + 1240000);

  // one-time: repack Wd and (Wx2+Wh2) into f16 hi/lo MFMA fragments
  repack_w<<<16000, 256, 0, stream>>>(Wd, nullptr, (_Float16*)Wd_pk, V_DIM);
  repack_w<<<2048, 256, 0, stream>>>(Wx2, Wh2, (_Float16*)W2_pk, GATES);
  zero_kernel<<<47, 256, 0, stream>>>(out, 11904);

  // encoder: single step, zero initial state -> z = x@Wx1 + b1 (fp32, one-shot)
  gemm64_kernel<<<dim3(16, 4), 256, 0, stream>>>(inp, Wx1, zparts, E_DIM, GATES);
  gates_kernel<<<256, 256, 0, stream>>>(zparts, 4, b1, nullptr, h, c,
                                        (_Float16*)hpkA);  // slot 0 = h_0

  // Phase A: pure state recurrence (sampling never feeds back): slots 1..31.
  for (int t = 0; t < T_STEPS; t++) {
    mfma_gemm<<<dim3(16, 8), 256, 0, stream>>>(
        (const half8*)(hpkA + (size_t)t * 65536), (const half8*)W2_pk,
        zparts, GATES);
    gates_kernel<<<256, 256, 0, stream>>>(
        zparts, 8, b2, c, h, c, (_Float16*)(hpkA + (size_t)(t + 1) * 65536));
  }

  // Phase B: ONE fused dispatch for all 31 logits GEMMs + sampling stage 1.
  // 512-thread t-paired blocks, XCD-swizzled inside the kernel.
  mfma_logits_fused<<<dim3(NBLK2), 512, 0, stream>>>(
      (const half8*)hpkA, (const half8*)Wd_pk, bd,
      pm, ps, pt2, pbest, plb, pbi);

  // Phase C: one batched stage-2 reduction for all (b, t)
  sample_stage2_batch<<<dim3(B_DIM, T_STEPS), 128, 0, stream>>>(
      pm, ps, pt2, pbest, plb, pbi, out);

  copy_kernel<<<256, 256, 0, stream>>>(h, out + 11904, B_DIM * H_DIM);
}